// Round 15
// baseline (249.069 us; speedup 1.0000x reference)
//
#include <hip/hip_runtime.h>
#include <hip/hip_bf16.h>

// QKVAttention: qkv (4,1536,2048) fp32, N_HEADS=8, ch=64, 32 total heads.
// S[t,s] = (1/8) sum_c q[c,t] k[c,s]; P = softmax over t (COLUMN softmax);
// a[c,t] = sum_s P[t,s] v[c,s].
//
//  K1 convert : Qt[h][t][c], Kt[h][s][c] bf16, transposed, XOR-pre-swizzled,
//               scale sqrt(0.125*log2e) baked in (so exp(S) == exp2(S')).
//  K2 statsA  : grid 512 (head x s-256 x T-HALF), 2 blocks/CU. Partial
//               l[s] sums via unsafeAtomicAdd into zeroed l_ws (2 commuting
//               contributors -> bitwise deterministic).
//  K3 statsB  : tiny V-scale: rl = 1/l, Vb = bf16(V*rl), 8-slot XOR
//               pre-swizzle per 64-s group.
//  K4 attnA   : grid 512 (head x t-256 x S-HALF), 2 blocks/CU, attn13's
//               verified 2:1-reuse inner loop over 16 chunks; in-block
//               s-pair exchange, then unsafeAtomicAdd into zeroed out.
//  EXP FIX    : __ocml_native_exp2_f32 (bare v_exp_f32) — R12's 40-us win.

#define SEQ   2048
#define CHD   64
#define NHB   32
#define SCALE_QK 0.42466090f   // sqrt(0.125 * log2(e))

typedef short bf16x8 __attribute__((ext_vector_type(8)));
typedef float f32x4  __attribute__((ext_vector_type(4)));
typedef float f32x16 __attribute__((ext_vector_type(16)));
typedef unsigned int   u32x4 __attribute__((ext_vector_type(4)));
typedef unsigned short us8   __attribute__((ext_vector_type(8)));

extern "C" __device__ float __ocml_native_exp2_f32(float);   // bare v_exp_f32
#define EXP2(x) __ocml_native_exp2_f32(x)

__device__ __forceinline__ unsigned short f2bf(float f) {
    unsigned int u = __builtin_bit_cast(unsigned int, f);
    u += 0x7FFFu + ((u >> 16) & 1u);   // RNE
    return (unsigned short)(u >> 16);
}

__device__ __forceinline__ void gl_lds16(const void* g, void* l) {
    __builtin_amdgcn_global_load_lds(
        (const __attribute__((address_space(1))) void*)g,
        (__attribute__((address_space(3))) void*)l, 16, 0, 0);
}

__device__ __forceinline__ unsigned cvtpk(float a, float b) {
    unsigned r;
    asm("v_cvt_pk_bf16_f32 %0, %1, %2" : "=v"(r) : "v"(a), "v"(b));
    return r;
}
__device__ __forceinline__ void plswap(unsigned &a, unsigned &b) {
    asm("v_permlane32_swap_b32 %0, %1" : "+v"(a), "+v"(b));
}

#define ZERO16 {0.f,0.f,0.f,0.f,0.f,0.f,0.f,0.f,0.f,0.f,0.f,0.f,0.f,0.f,0.f,0.f}

// ------------------------------------------------ K1: transpose+convert Q,K
__global__ __launch_bounds__(256) void convert_qk(
    const float* __restrict__ qkv, unsigned short* __restrict__ Qt,
    unsigned short* __restrict__ Kt)
{
    __shared__ float Tl[64][129];
    const int bid = blockIdx.x;
    const int head = bid >> 4, t0 = (bid & 15) * 128;
    const int b = head >> 3, h = head & 7;
    const float* base = qkv + (size_t)(b * 1536 + h * 192) * SEQ;
    const int tid = threadIdx.x;
#pragma unroll
    for (int pp = 0; pp < 2; ++pp) {
        const float* src = base + (size_t)(pp ? CHD : 0) * SEQ;
        unsigned short* dst = (pp ? Kt : Qt) + (size_t)head * SEQ * CHD;
        if (pp) __syncthreads();
        for (int e = tid; e < 8192; e += 256) {
            int c = e >> 7, ti = e & 127;
            Tl[c][ti] = src[(size_t)c * SEQ + t0 + ti];
        }
        __syncthreads();
        for (int g = tid; g < 1024; g += 256) {
            int t = g >> 3, cg = g & 7;
            us8 u;
#pragma unroll
            for (int j = 0; j < 8; ++j) u[j] = f2bf(Tl[cg * 8 + j][t] * SCALE_QK);
            *(us8*)(dst + (size_t)(t0 + t) * 64 + ((cg * 8) ^ ((t & 7) << 3))) = u;
        }
    }
}

// ------------------------------------------------ K2: partial column sums
// grid 512: head x s-tile(256) x t-half. 8 waves x 32 s; K in registers.
__global__ __launch_bounds__(512, 4) void statsA_kernel(
    const unsigned short* __restrict__ Qt, const unsigned short* __restrict__ Kt,
    float* __restrict__ l_ws)
{
    __shared__ __attribute__((aligned(16))) unsigned short Qs[4][4096]; // 32 KB
    const int bid = blockIdx.x;
    const int bs  = ((bid & 7) << 6) | (bid >> 3);   // XCD swizzle (512%8==0)
    const int head = bs >> 4, s0 = ((bs >> 1) & 7) * 256, tH = bs & 1;
    const char* Qhb = (const char*)(Qt + (size_t)head * SEQ * CHD);
    const unsigned short* Kh = Kt + (size_t)head * SEQ * CHD;
    const int tid = threadIdx.x, w = tid >> 6, l = tid & 63, lo5 = l & 31, hi = l >> 5;
    const int rsw = (lo5 & 7) << 3;

    // this wave's 32 s, K register-resident
    bf16x8 kfr[4];
#pragma unroll
    for (int kc = 0; kc < 4; ++kc)
        kfr[kc] = *(const bf16x8*)(
            Kh + (size_t)(s0 + w * 32 + lo5) * 64 + (((kc << 4) + (hi << 3)) ^ rsw));

    auto stage = [&](int p, int tc) {
        gl_lds16(Qhb + (size_t)(tH * 16 + tc) * 8192 + tid * 16, &Qs[p][0] + tid * 8);
    };

    float lacc[4] = {0.f, 0.f, 0.f, 0.f};

    stage(0, 0);
    stage(1, 1);
    for (int tc = 0; tc < 16; ++tc) {
        if (tc < 15) asm volatile("s_waitcnt vmcnt(1)" ::: "memory");
        else         asm volatile("s_waitcnt vmcnt(0)" ::: "memory");
        __builtin_amdgcn_s_barrier();
        __builtin_amdgcn_sched_barrier(0);
        if (tc < 14) stage((tc + 2) & 3, tc + 2);
        const unsigned short* qs = &Qs[tc & 3][0];
        __builtin_amdgcn_s_setprio(1);
#pragma unroll
        for (int ts = 0; ts < 2; ++ts) {
            f32x16 s = ZERO16;
#pragma unroll
            for (int kc = 0; kc < 4; ++kc) {
                bf16x8 qa = *(const bf16x8*)(
                    qs + (ts * 32 + lo5) * 64 + (((kc << 4) + (hi << 3)) ^ rsw));
                s = __builtin_amdgcn_mfma_f32_32x32x16_bf16(qa, kfr[kc], s, 0, 0, 0);
            }
#pragma unroll
            for (int r = 0; r < 16; ++r) lacc[r & 3] += EXP2(s[r]);
        }
        __builtin_amdgcn_s_setprio(0);
    }

    float lsum = (lacc[0] + lacc[1]) + (lacc[2] + lacc[3]);
    lsum += __shfl_xor(lsum, 32);
    if (l < 32) unsafeAtomicAdd(&l_ws[head * SEQ + s0 + w * 32 + lo5], lsum);
}

// ------------------------------------------------ K3: V-scale (memory-bound)
// grid 256: head x s-tile(256); Vb = bf16(V/l), 8-slot XOR per 64-s group.
__global__ __launch_bounds__(256) void statsB_kernel(
    const float* __restrict__ qkv, const float* __restrict__ l_ws,
    unsigned short* __restrict__ Vb)
{
    __shared__ float rlb[256];
    const int bid = blockIdx.x;
    const int bs  = ((bid & 7) << 5) | (bid >> 3);   // XCD swizzle (256%8==0)
    const int head = bs >> 3, s0 = (bs & 7) * 256;
    const int b = head >> 3, h = head & 7;
    const int tid = threadIdx.x;

    rlb[tid] = 1.0f / l_ws[head * SEQ + s0 + tid];
    __syncthreads();

    const float* vp = qkv + (size_t)(b * 1536 + h * 192 + 2 * CHD) * SEQ;
    unsigned short* Vh = Vb + (size_t)head * SEQ * CHD;   // layout [c][2048]
    for (int g = tid; g < 2048; g += 256) {
        int c = g >> 5, si8 = (g & 31) * 8;
        const float* vrow = vp + (size_t)c * SEQ + s0 + si8;
        f32x4 v0 = *(const f32x4*)(vrow);
        f32x4 v1 = *(const f32x4*)(vrow + 4);
        us8 u;
#pragma unroll
        for (int j = 0; j < 4; ++j) u[j]     = f2bf(v0[j] * rlb[si8 + j]);
#pragma unroll
        for (int j = 0; j < 4; ++j) u[4 + j] = f2bf(v1[j] * rlb[si8 + 4 + j]);
        int swb = (si8 & ~63) | ((si8 & 63) ^ ((c & 7) << 3));
        *(us8*)(Vh + (size_t)c * SEQ + s0 + swb) = u;
    }
}

// ------------------------------------------------ K4: attention (s-half grid)
// grid 512: head x t-tile(256) x s-half. 8 waves = 4 t-sub(64t) x 2 wave-s-
// halves; 16 chunks of 64 s; 4 LDS bufs, 1 barrier/chunk, vmcnt(2).
__global__ __launch_bounds__(512, 4) void attnA_kernel(
    const unsigned short* __restrict__ Qt, const unsigned short* __restrict__ Kt,
    const unsigned short* __restrict__ Vb, float* __restrict__ out)
{
    __shared__ __attribute__((aligned(16))) unsigned short KV[4][8192]; // 64 KB
    const int bid = blockIdx.x;
    const int bs  = ((bid & 7) << 6) | (bid >> 3);   // XCD swizzle (512%8==0)
    const int head = bs >> 4, t0 = ((bs >> 1) & 7) * 256, sH = bs & 1;
    const int cbase = sH * 16;                       // this block's chunk base
    const int b = head >> 3, h = head & 7;
    const int tid = threadIdx.x, w = tid >> 6, l = tid & 63, lo5 = l & 31, hi = l >> 5;
    const int tw = w >> 1, sh = w & 1;
    const int rsw = (lo5 & 7) << 3;
    const unsigned short* Qh = Qt + (size_t)head * SEQ * CHD;
    const char* Khb = (const char*)(Kt + (size_t)head * SEQ * CHD);
    const char* Vhb = (const char*)(Vb + (size_t)head * SEQ * CHD);

    // Q B-fragments for this wave's 2 t-sets (64 t), register-resident
    bf16x8 qfA[4], qfB[4];
#pragma unroll
    for (int kc = 0; kc < 4; ++kc) {
        qfA[kc] = *(const bf16x8*)(
            Qh + (size_t)(t0 + tw * 64 + lo5) * 64 + (((kc << 4) + (hi << 3)) ^ rsw));
        qfB[kc] = *(const bf16x8*)(
            Qh + (size_t)(t0 + tw * 64 + 32 + lo5) * 64 + (((kc << 4) + (hi << 3)) ^ rsw));
    }

    f32x16 accA0 = ZERO16, accA1 = ZERO16, accB0 = ZERO16, accB1 = ZERO16;

    const int vc = tid >> 3, vs16 = (tid & 7) * 16;
    auto stage = [&](int p, int cj) {
        unsigned short* kb = &KV[p][0];
        unsigned short* vb = &KV[p][4096];
        gl_lds16(Khb + (size_t)cj * 8192 + tid * 16, kb + tid * 8);
        gl_lds16(Vhb + (size_t)vc * 4096 + (size_t)cj * 128 + vs16, vb + tid * 8);
    };

    stage(0, cbase + 0);
    stage(1, cbase + 1);

    for (int j = 0; j < 16; ++j) {
        const int p = j & 3;
        if (j < 15) asm volatile("s_waitcnt vmcnt(2)" ::: "memory");
        else        asm volatile("s_waitcnt vmcnt(0)" ::: "memory");
        __builtin_amdgcn_s_barrier();
        __builtin_amdgcn_sched_barrier(0);
        if (j < 14) stage((j + 2) & 3, cbase + j + 2);

        const unsigned short* kb = &KV[p][0];
        const unsigned short* vb = &KV[p][4096];

        bf16x8 kf[4], vf0k0, vf0k1, vf1k0, vf1k1;
#pragma unroll
        for (int kc = 0; kc < 4; ++kc)
            kf[kc] = *(const bf16x8*)(
                kb + (sh * 32 + lo5) * 64 + (((kc << 4) + (hi << 3)) ^ rsw));
        vf0k0 = *(const bf16x8*)(vb + (lo5) * 64       + ((sh * 32 +      (hi << 3)) ^ rsw));
        vf0k1 = *(const bf16x8*)(vb + (lo5) * 64       + ((sh * 32 + 16 + (hi << 3)) ^ rsw));
        vf1k0 = *(const bf16x8*)(vb + (32 + lo5) * 64  + ((sh * 32 +      (hi << 3)) ^ rsw));
        vf1k1 = *(const bf16x8*)(vb + (32 + lo5) * 64  + ((sh * 32 + 16 + (hi << 3)) ^ rsw));

        __builtin_amdgcn_s_setprio(1);
        f32x16 SA = ZERO16, SB = ZERO16;
#pragma unroll
        for (int kc = 0; kc < 4; ++kc)
            SA = __builtin_amdgcn_mfma_f32_32x32x16_bf16(kf[kc], qfA[kc], SA, 0, 0, 0);
#pragma unroll
        for (int kc = 0; kc < 4; ++kc)
            SB = __builtin_amdgcn_mfma_f32_32x32x16_bf16(kf[kc], qfB[kc], SB, 0, 0, 0);

        {
            float p16[16];
#pragma unroll
            for (int r = 0; r < 16; ++r) p16[r] = EXP2(SA[r]);
            unsigned w0 = cvtpk(p16[0],  p16[1]),  w1 = cvtpk(p16[2],  p16[3]);
            unsigned w2 = cvtpk(p16[4],  p16[5]),  w3 = cvtpk(p16[6],  p16[7]);
            unsigned w4 = cvtpk(p16[8],  p16[9]),  w5 = cvtpk(p16[10], p16[11]);
            unsigned w6 = cvtpk(p16[12], p16[13]), w7 = cvtpk(p16[14], p16[15]);
            plswap(w0, w2); plswap(w1, w3); plswap(w4, w6); plswap(w5, w7);
            bf16x8 pfA = __builtin_bit_cast(bf16x8, (u32x4){w0, w1, w2, w3});
            bf16x8 pfB = __builtin_bit_cast(bf16x8, (u32x4){w4, w5, w6, w7});
            accA0 = __builtin_amdgcn_mfma_f32_32x32x16_bf16(vf0k0, pfA, accA0, 0, 0, 0);
            accA0 = __builtin_amdgcn_mfma_f32_32x32x16_bf16(vf0k1, pfB, accA0, 0, 0, 0);
            accA1 = __builtin_amdgcn_mfma_f32_32x32x16_bf16(vf1k0, pfA, accA1, 0, 0, 0);
            accA1 = __builtin_amdgcn_mfma_f32_32x32x16_bf16(vf1k1, pfB, accA1, 0, 0, 0);
        }
        {
            float p16[16];
#pragma unroll
            for (int r = 0; r < 16; ++r) p16[r] = EXP2(SB[r]);
            unsigned w0 = cvtpk(p16[0],  p16[1]),  w1 = cvtpk(p16[2],  p16[3]);
            unsigned w2 = cvtpk(p16[4],  p16[5]),  w3 = cvtpk(p16[6],  p16[7]);
            unsigned w4 = cvtpk(p16[8],  p16[9]),  w5 = cvtpk(p16[10], p16[11]);
            unsigned w6 = cvtpk(p16[12], p16[13]), w7 = cvtpk(p16[14], p16[15]);
            plswap(w0, w2); plswap(w1, w3); plswap(w4, w6); plswap(w5, w7);
            bf16x8 pfA = __builtin_bit_cast(bf16x8, (u32x4){w0, w1, w2, w3});
            bf16x8 pfB = __builtin_bit_cast(bf16x8, (u32x4){w4, w5, w6, w7});
            accB0 = __builtin_amdgcn_mfma_f32_32x32x16_bf16(vf0k0, pfA, accB0, 0, 0, 0);
            accB0 = __builtin_amdgcn_mfma_f32_32x32x16_bf16(vf0k1, pfB, accB0, 0, 0, 0);
            accB1 = __builtin_amdgcn_mfma_f32_32x32x16_bf16(vf1k0, pfA, accB1, 0, 0, 0);
            accB1 = __builtin_amdgcn_mfma_f32_32x32x16_bf16(vf1k1, pfB, accB1, 0, 0, 0);
        }
        __builtin_amdgcn_s_setprio(0);
    }

    // ---- in-block s-pair exchange (partner = w^1). Wave keeps c-half == sh.
    __syncthreads();
    float* red = (float*)&KV[0][0];
    if (sh == 0) {
        *(f32x16*)(red + (size_t)w * 2048 + l * 16)        = accA1;
        *(f32x16*)(red + (size_t)w * 2048 + 1024 + l * 16) = accB1;
    } else {
        *(f32x16*)(red + (size_t)w * 2048 + l * 16)        = accA0;
        *(f32x16*)(red + (size_t)w * 2048 + 1024 + l * 16) = accB0;
    }
    __syncthreads();
    f32x16 pA = *(const f32x16*)(red + (size_t)(w ^ 1) * 2048 + l * 16);
    f32x16 pB = *(const f32x16*)(red + (size_t)(w ^ 1) * 2048 + 1024 + l * 16);
    f32x16 finA, finB;
    if (sh == 0) { finA = accA0 + pA; finB = accB0 + pB; }
    else         { finA = accA1 + pA; finB = accB1 + pB; }

    // ---- cross-block combine: 2 commuting atomic adds into zeroed out.
    float* op = out + (size_t)(b * 512 + h * 64) * SEQ;
    const int tA = t0 + tw * 64 + lo5, tB = tA + 32;
#pragma unroll
    for (int r = 0; r < 16; ++r) {
        int c = sh * 32 + (r & 3) + 8 * (r >> 2) + 4 * hi;
        unsafeAtomicAdd(&op[(size_t)c * SEQ + tA], finA[r]);
        unsafeAtomicAdd(&op[(size_t)c * SEQ + tB], finB[r]);
    }
}

// ================================================================ fallback
// (round-1 proven path, used only if ws is too small for the bf16 buffers)

__device__ __forceinline__ bf16x8 lds_frag(const unsigned short* base, int row, int el) {
    int e = el ^ ((row & 7) << 3);
    return *(const bf16x8*)(base + row * 64 + e);
}

__global__ __launch_bounds__(256) void qkv_stats_kernel(
    const float* __restrict__ qkv, float* __restrict__ m_ws, float* __restrict__ rl_ws)
{
    __shared__ __attribute__((aligned(16))) unsigned short Kl[128 * 64];
    __shared__ __attribute__((aligned(16))) unsigned short Ql[64 * 64];
    const int head = blockIdx.x >> 4, stile = blockIdx.x & 15, s0 = stile * 128;
    const int b = head >> 3, h = head & 7;
    const float* qp = qkv + (size_t)(b * 1536 + h * 192) * SEQ;
    const float* kp = qp + (size_t)CHD * SEQ;
    const int tid = threadIdx.x, w = tid >> 6, l = tid & 63, lg = l >> 4, lr = l & 15;
    for (int idx = tid; idx < 128 * 64; idx += 256) {
        int s = idx & 127, c = idx >> 7;
        Kl[s * 64 + (c ^ ((s & 7) << 3))] = f2bf(kp[(size_t)c * SEQ + s0 + s]);
    }
    float m_run[2] = {-__builtin_inff(), -__builtin_inff()};
    float l_run[2] = {0.f, 0.f};
    for (int chunk = 0; chunk < 32; ++chunk) {
        const int t0 = chunk * 64;
        __syncthreads();
        for (int idx = tid; idx < 64 * 64; idx += 256) {
            int t = idx & 63, c = idx >> 6;
            Ql[t * 64 + (c ^ ((t & 7) << 3))] = f2bf(qp[(size_t)c * SEQ + t0 + t]);
        }
        __syncthreads();
#pragma unroll
        for (int ntl = 0; ntl < 2; ++ntl) {
            const int srow = 16 * (2 * w + ntl) + lr;
            float vals[16];
#pragma unroll
            for (int mt = 0; mt < 4; ++mt) {
                f32x4 sacc = {0.f, 0.f, 0.f, 0.f};
#pragma unroll
                for (int kk = 0; kk < 2; ++kk) {
                    bf16x8 a  = lds_frag(Ql, 16 * mt + lr, 32 * kk + 8 * lg);
                    bf16x8 bk = lds_frag(Kl, srow,         32 * kk + 8 * lg);
                    sacc = __builtin_amdgcn_mfma_f32_16x16x32_bf16(a, bk, sacc, 0, 0, 0);
                }
#pragma unroll
                for (int j = 0; j < 4; ++j) vals[mt * 4 + j] = sacc[j] * 0.125f;
            }
            float cm = vals[0];
#pragma unroll
            for (int i = 1; i < 16; ++i) cm = fmaxf(cm, vals[i]);
            cm = fmaxf(cm, __shfl_xor(cm, 16));
            cm = fmaxf(cm, __shfl_xor(cm, 32));
            float newm = fmaxf(m_run[ntl], cm);
            l_run[ntl] *= __expf(m_run[ntl] - newm);
            m_run[ntl] = newm;
            float ps = 0.f;
#pragma unroll
            for (int i = 0; i < 16; ++i) ps += __expf(vals[i] - newm);
            ps += __shfl_xor(ps, 16);
            ps += __shfl_xor(ps, 32);
            l_run[ntl] += ps;
        }
    }
    if (lg == 0) {
#pragma unroll
        for (int ntl = 0; ntl < 2; ++ntl) {
            int sg = s0 + 16 * (2 * w + ntl) + lr;
            m_ws[head * SEQ + sg]  = m_run[ntl];
            rl_ws[head * SEQ + sg] = 1.0f / l_run[ntl];
        }
    }
}

__global__ __launch_bounds__(256) void qkv_attn_kernel(
    const float* __restrict__ qkv, const float* __restrict__ m_ws,
    const float* __restrict__ rl_ws, float* __restrict__ out)
{
    __shared__ __attribute__((aligned(16))) unsigned short Ql[128 * 64];
    __shared__ __attribute__((aligned(16))) unsigned short Kl[64 * 64];
    __shared__ __attribute__((aligned(16))) unsigned short Vl[64 * 64];
    __shared__ __attribute__((aligned(16))) unsigned short Pl[128 * 64];
    const int head = blockIdx.x >> 4, ttile = blockIdx.x & 15, t0 = ttile * 128;
    const int b = head >> 3, h = head & 7;
    const float* qp  = qkv + (size_t)(b * 1536 + h * 192) * SEQ;
    const float* kp  = qp + (size_t)CHD * SEQ;
    const float* vp  = qp + (size_t)(2 * CHD) * SEQ;
    const float* mh  = m_ws  + head * SEQ;
    const float* rlh = rl_ws + head * SEQ;
    const int tid = threadIdx.x, w = tid >> 6, l = tid & 63, lg = l >> 4, lr = l & 15;
    for (int idx = tid; idx < 128 * 64; idx += 256) {
        int t = idx & 127, c = idx >> 7;
        Ql[t * 64 + (c ^ ((t & 7) << 3))] = f2bf(qp[(size_t)c * SEQ + t0 + t]);
    }
    f32x4 acc[4][2];
#pragma unroll
    for (int i = 0; i < 4; ++i)
#pragma unroll
        for (int j = 0; j < 2; ++j) acc[i][j] = (f32x4){0.f, 0.f, 0.f, 0.f};
    for (int sc = 0; sc < 32; ++sc) {
        const int s0 = sc * 64;
        __syncthreads();
        for (int idx = tid; idx < 64 * 64; idx += 256) {
            int s = idx & 63, c = idx >> 6;
            Kl[s * 64 + (c ^ ((s & 7) << 3))] = f2bf(kp[(size_t)c * SEQ + s0 + s]);
            Vl[c * 64 + (s ^ ((c & 7) << 3))] = f2bf(vp[(size_t)c * SEQ + s0 + s] * rlh[s0 + s]);
        }
        __syncthreads();
        float msv[4];
#pragma unroll
        for (int nts = 0; nts < 4; ++nts) msv[nts] = mh[s0 + 16 * nts + lr];
#pragma unroll
        for (int mts = 0; mts < 2; ++mts) {
            const int trowbase = 16 * (2 * w + mts);
#pragma unroll
            for (int nts = 0; nts < 4; ++nts) {
                f32x4 sa = {0.f, 0.f, 0.f, 0.f};
#pragma unroll
                for (int kk = 0; kk < 2; ++kk) {
                    bf16x8 a  = lds_frag(Ql, trowbase + lr, 32 * kk + 8 * lg);
                    bf16x8 bk = lds_frag(Kl, 16 * nts + lr, 32 * kk + 8 * lg);
                    sa = __builtin_amdgcn_mfma_f32_16x16x32_bf16(a, bk, sa, 0, 0, 0);
                }
                const int scol = 16 * nts + lr;
#pragma unroll
                for (int j = 0; j < 4; ++j) {
                    int trow = trowbase + 4 * lg + j;
                    float p = __expf(sa[j] * 0.125f - msv[nts]);
                    Pl[trow * 64 + (scol ^ ((trow & 7) << 3))] = f2bf(p);
                }
            }
        }
#pragma unroll
        for (int mt = 0; mt < 4; ++mt) {
#pragma unroll
            for (int ntl = 0; ntl < 2; ++ntl) {
                const int trow = 16 * (2 * w + ntl);
#pragma unroll
                for (int kk = 0; kk < 2; ++kk) {
                    bf16x8 a  = lds_frag(Vl, 16 * mt + lr, 32 * kk + 8 * lg);
                    bf16x8 bp = lds_frag(Pl, trow + lr,    32 * kk + 8 * lg);
                    acc[mt][ntl] = __builtin_amdgcn_mfma_f32_16x16x32_bf16(a, bp, acc[mt][ntl], 0, 0, 0);
                }
            }
        }
    }
    float* op = out + (size_t)(b * 512 + h * 64) * SEQ;
#pragma unroll
    for (int mt = 0; mt < 4; ++mt) {
#pragma unroll
        for (int ntl = 0; ntl < 2; ++ntl) {
            int tcol = t0 + 16 * (2 * w + ntl) + lr;
#pragma unroll
            for (int j = 0; j < 4; ++j) {
                int c = 16 * mt + 4 * lg + j;
                op[(size_t)c * SEQ + tcol] = acc[mt][ntl][j];
            }
        }
    }
}

// ================================================================ launch
extern "C" void kernel_launch(void* const* d_in, const int* in_sizes, int n_in,
                              void* d_out, int out_size, void* d_ws, size_t ws_size,
                              hipStream_t stream) {
    const float* qkv = (const float*)d_in[0];
    float* out = (float*)d_out;
    (void)in_sizes; (void)n_in;

    const size_t bufE = (size_t)NHB * SEQ * CHD;           // elements per buffer
    const size_t need = 3 * bufE * 2 + (size_t)NHB * SEQ * 4;  // 24 MB + l_ws
    if (ws_size >= need) {
        unsigned short* Qt = (unsigned short*)d_ws;
        unsigned short* Kt = Qt + bufE;
        unsigned short* Vb = Kt + bufE;
        float* l_ws = (float*)(Vb + bufE);
        hipMemsetAsync(l_ws, 0, (size_t)NHB * SEQ * 4, stream);
        hipMemsetAsync(out, 0, (size_t)out_size * 4, stream);
        convert_qk   <<<dim3(NHB * 16), dim3(256), 0, stream>>>(qkv, Qt, Kt);
        statsA_kernel<<<dim3(512),      dim3(512), 0, stream>>>(Qt, Kt, l_ws);
        statsB_kernel<<<dim3(256),      dim3(256), 0, stream>>>(qkv, l_ws, Vb);
        attnA_kernel <<<dim3(512),      dim3(512), 0, stream>>>(Qt, Kt, Vb, out);
    } else {
        float* m_ws  = (float*)d_ws;
        float* rl_ws = m_ws + (size_t)NHB * SEQ;
        qkv_stats_kernel<<<dim3(NHB * 16), dim3(256), 0, stream>>>(qkv, m_ws, rl_ws);
        qkv_attn_kernel <<<dim3(NHB * 16), dim3(256), 0, stream>>>(qkv, m_ws, rl_ws, out);
    }
}

// Round 17
// 240.024 us; speedup vs baseline: 1.0377x; 1.0377x over previous
//
#include <hip/hip_runtime.h>
#include <hip/hip_bf16.h>

// QKVAttention: qkv (4,1536,2048) fp32, N_HEADS=8, ch=64, 32 total heads.
// S[t,s] = (1/8) sum_c q[c,t] k[c,s]; P = softmax over t (COLUMN softmax);
// a[c,t] = sum_s P[t,s] v[c,s].
//
//  K1 convert : Qt[h][t][c], Kt[h][s][c] bf16, transposed, XOR-pre-swizzled.
//  K2 statsA  : grid 512 (head x s-256 x T-HALF), 2 blocks/CU; tiny
//               unsafeAtomicAdd partials into zeroed l_ws.
//  K3 statsB  : V-scale: Vb = bf16(V/l), 8-slot XOR per 64-s group.
//  K4 attn14b : grid 512 = head x 16 t-tiles(128 t) -> 2 blocks/CU. 8 waves
//               = 2 t-subs(64t, 2 Q-sets) x 4 s-quarters over 128-s chunks
//               (2 LDS bufs x 32 KB). In-block 4-way s-reduction via two
//               pairwise LDS exchanges. R16 BUG FIX: V second-half LDS dest
//               is vb+4096 ELEMENTS (was 8192 -> OOB write + poison reads).
//  EXP FIX    : __ocml_native_exp2_f32 (bare v_exp_f32).

#define SEQ   2048
#define CHD   64
#define NHB   32
#define SCALE_QK 0.42466090f   // sqrt(0.125 * log2(e))

typedef short bf16x8 __attribute__((ext_vector_type(8)));
typedef float f32x4  __attribute__((ext_vector_type(4)));
typedef float f32x16 __attribute__((ext_vector_type(16)));
typedef unsigned int   u32x4 __attribute__((ext_vector_type(4)));
typedef unsigned short us8   __attribute__((ext_vector_type(8)));

extern "C" __device__ float __ocml_native_exp2_f32(float);   // bare v_exp_f32
#define EXP2(x) __ocml_native_exp2_f32(x)

__device__ __forceinline__ unsigned short f2bf(float f) {
    unsigned int u = __builtin_bit_cast(unsigned int, f);
    u += 0x7FFFu + ((u >> 16) & 1u);   // RNE
    return (unsigned short)(u >> 16);
}

__device__ __forceinline__ void gl_lds16(const void* g, void* l) {
    __builtin_amdgcn_global_load_lds(
        (const __attribute__((address_space(1))) void*)g,
        (__attribute__((address_space(3))) void*)l, 16, 0, 0);
}

__device__ __forceinline__ unsigned cvtpk(float a, float b) {
    unsigned r;
    asm("v_cvt_pk_bf16_f32 %0, %1, %2" : "=v"(r) : "v"(a), "v"(b));
    return r;
}
__device__ __forceinline__ void plswap(unsigned &a, unsigned &b) {
    asm("v_permlane32_swap_b32 %0, %1" : "+v"(a), "+v"(b));
}

#define ZERO16 {0.f,0.f,0.f,0.f,0.f,0.f,0.f,0.f,0.f,0.f,0.f,0.f,0.f,0.f,0.f,0.f}

// ------------------------------------------------ K1: transpose+convert Q,K
__global__ __launch_bounds__(256) void convert_qk(
    const float* __restrict__ qkv, unsigned short* __restrict__ Qt,
    unsigned short* __restrict__ Kt)
{
    __shared__ float Tl[64][129];
    const int bid = blockIdx.x;
    const int head = bid >> 4, t0 = (bid & 15) * 128;
    const int b = head >> 3, h = head & 7;
    const float* base = qkv + (size_t)(b * 1536 + h * 192) * SEQ;
    const int tid = threadIdx.x;
#pragma unroll
    for (int pp = 0; pp < 2; ++pp) {
        const float* src = base + (size_t)(pp ? CHD : 0) * SEQ;
        unsigned short* dst = (pp ? Kt : Qt) + (size_t)head * SEQ * CHD;
        if (pp) __syncthreads();
        for (int e = tid; e < 8192; e += 256) {
            int c = e >> 7, ti = e & 127;
            Tl[c][ti] = src[(size_t)c * SEQ + t0 + ti];
        }
        __syncthreads();
        for (int g = tid; g < 1024; g += 256) {
            int t = g >> 3, cg = g & 7;
            us8 u;
#pragma unroll
            for (int j = 0; j < 8; ++j) u[j] = f2bf(Tl[cg * 8 + j][t] * SCALE_QK);
            *(us8*)(dst + (size_t)(t0 + t) * 64 + ((cg * 8) ^ ((t & 7) << 3))) = u;
        }
    }
}

// ------------------------------------------------ K2: partial column sums
__global__ __launch_bounds__(512, 4) void statsA_kernel(
    const unsigned short* __restrict__ Qt, const unsigned short* __restrict__ Kt,
    float* __restrict__ l_ws)
{
    __shared__ __attribute__((aligned(16))) unsigned short Qs[4][4096]; // 32 KB
    const int bid = blockIdx.x;
    const int bs  = ((bid & 7) << 6) | (bid >> 3);   // XCD swizzle (512%8==0)
    const int head = bs >> 4, s0 = ((bs >> 1) & 7) * 256, tH = bs & 1;
    const char* Qhb = (const char*)(Qt + (size_t)head * SEQ * CHD);
    const unsigned short* Kh = Kt + (size_t)head * SEQ * CHD;
    const int tid = threadIdx.x, w = tid >> 6, l = tid & 63, lo5 = l & 31, hi = l >> 5;
    const int rsw = (lo5 & 7) << 3;

    bf16x8 kfr[4];
#pragma unroll
    for (int kc = 0; kc < 4; ++kc)
        kfr[kc] = *(const bf16x8*)(
            Kh + (size_t)(s0 + w * 32 + lo5) * 64 + (((kc << 4) + (hi << 3)) ^ rsw));

    auto stage = [&](int p, int tc) {
        gl_lds16(Qhb + (size_t)(tH * 16 + tc) * 8192 + tid * 16, &Qs[p][0] + tid * 8);
    };

    float lacc[4] = {0.f, 0.f, 0.f, 0.f};

    stage(0, 0);
    stage(1, 1);
    for (int tc = 0; tc < 16; ++tc) {
        if (tc < 15) asm volatile("s_waitcnt vmcnt(1)" ::: "memory");
        else         asm volatile("s_waitcnt vmcnt(0)" ::: "memory");
        __builtin_amdgcn_s_barrier();
        __builtin_amdgcn_sched_barrier(0);
        if (tc < 14) stage((tc + 2) & 3, tc + 2);
        const unsigned short* qs = &Qs[tc & 3][0];
        __builtin_amdgcn_s_setprio(1);
#pragma unroll
        for (int ts = 0; ts < 2; ++ts) {
            f32x16 s = ZERO16;
#pragma unroll
            for (int kc = 0; kc < 4; ++kc) {
                bf16x8 qa = *(const bf16x8*)(
                    qs + (ts * 32 + lo5) * 64 + (((kc << 4) + (hi << 3)) ^ rsw));
                s = __builtin_amdgcn_mfma_f32_32x32x16_bf16(qa, kfr[kc], s, 0, 0, 0);
            }
#pragma unroll
            for (int r = 0; r < 16; ++r) lacc[r & 3] += EXP2(s[r]);
        }
        __builtin_amdgcn_s_setprio(0);
    }

    float lsum = (lacc[0] + lacc[1]) + (lacc[2] + lacc[3]);
    lsum += __shfl_xor(lsum, 32);
    if (l < 32) unsafeAtomicAdd(&l_ws[head * SEQ + s0 + w * 32 + lo5], lsum);
}

// ------------------------------------------------ K3: V-scale (memory-bound)
__global__ __launch_bounds__(256) void statsB_kernel(
    const float* __restrict__ qkv, const float* __restrict__ l_ws,
    unsigned short* __restrict__ Vb)
{
    __shared__ float rlb[256];
    const int bid = blockIdx.x;
    const int bs  = ((bid & 7) << 5) | (bid >> 3);   // XCD swizzle (256%8==0)
    const int head = bs >> 3, s0 = (bs & 7) * 256;
    const int b = head >> 3, h = head & 7;
    const int tid = threadIdx.x;

    rlb[tid] = 1.0f / l_ws[head * SEQ + s0 + tid];
    __syncthreads();

    const float* vp = qkv + (size_t)(b * 1536 + h * 192 + 2 * CHD) * SEQ;
    unsigned short* Vh = Vb + (size_t)head * SEQ * CHD;   // layout [c][2048]
    for (int g = tid; g < 2048; g += 256) {
        int c = g >> 5, si8 = (g & 31) * 8;
        const float* vrow = vp + (size_t)c * SEQ + s0 + si8;
        f32x4 v0 = *(const f32x4*)(vrow);
        f32x4 v1 = *(const f32x4*)(vrow + 4);
        us8 u;
#pragma unroll
        for (int j = 0; j < 4; ++j) u[j]     = f2bf(v0[j] * rlb[si8 + j]);
#pragma unroll
        for (int j = 0; j < 4; ++j) u[4 + j] = f2bf(v1[j] * rlb[si8 + 4 + j]);
        int swb = (si8 & ~63) | ((si8 & 63) ^ ((c & 7) << 3));
        *(us8*)(Vh + (size_t)c * SEQ + s0 + swb) = u;
    }
}

// ------------------------------------------------ K4: attention (t-split)
// grid 512 = head x 16 t-tiles(128t). 8 waves = 2 t-subs(64t) x 4 s-quarters.
// 128-s chunks, 2 LDS buffers (32 KB each).
__global__ __launch_bounds__(512, 4) void attn14_kernel(
    const unsigned short* __restrict__ Qt, const unsigned short* __restrict__ Kt,
    const unsigned short* __restrict__ Vb, float* __restrict__ out)
{
    __shared__ __attribute__((aligned(16))) unsigned short KV[2][16384]; // 64 KB
    const int bid = blockIdx.x;
    const int bs  = ((bid & 7) << 6) | (bid >> 3);   // XCD swizzle (512%8==0)
    const int head = bs >> 4, t0 = (bs & 15) * 128;
    const int b = head >> 3, h = head & 7;
    const int tid = threadIdx.x, w = tid >> 6, l = tid & 63, lo5 = l & 31, hi = l >> 5;
    const int tw = w >> 2, sq = w & 3;
    const int rsw = (lo5 & 7) << 3;
    const unsigned short* Qh = Qt + (size_t)head * SEQ * CHD;
    const char* Khb = (const char*)(Kt + (size_t)head * SEQ * CHD);
    const char* Vhb = (const char*)(Vb + (size_t)head * SEQ * CHD);

    // Q B-fragments for this wave's 2 t-sets (64 t), register-resident
    bf16x8 qfA[4], qfB[4];
#pragma unroll
    for (int kc = 0; kc < 4; ++kc) {
        qfA[kc] = *(const bf16x8*)(
            Qh + (size_t)(t0 + tw * 64 + lo5) * 64 + (((kc << 4) + (hi << 3)) ^ rsw));
        qfB[kc] = *(const bf16x8*)(
            Qh + (size_t)(t0 + tw * 64 + 32 + lo5) * 64 + (((kc << 4) + (hi << 3)) ^ rsw));
    }

    f32x16 accA0 = ZERO16, accA1 = ZERO16, accB0 = ZERO16, accB1 = ZERO16;

    // stage 128-s chunk cj: K 16 KB + V 16 KB; 4 loads per thread.
    // Each gl_lds16 sweep covers 512 thr x 8 elem = 4096 elements.
    const int vcr = tid >> 4, vs16 = (tid & 15) * 16;
    auto stage = [&](int p, int cj) {
        unsigned short* kb = &KV[p][0];
        unsigned short* vb = &KV[p][8192];
        gl_lds16(Khb + (size_t)cj * 16384 + tid * 16,        kb + tid * 8);
        gl_lds16(Khb + (size_t)cj * 16384 + 8192 + tid * 16, kb + 4096 + tid * 8);
        gl_lds16(Vhb + (size_t)vcr * 4096 + (size_t)cj * 256 + vs16, vb + tid * 8);
        gl_lds16(Vhb + (size_t)(vcr + 32) * 4096 + (size_t)cj * 256 + vs16,
                 vb + 4096 + tid * 8);   // FIX: was +8192 (OOB)
    };

    stage(0, 0);
    asm volatile("s_waitcnt vmcnt(0)" ::: "memory");
    __builtin_amdgcn_s_barrier();

    // V read column offsets (physical, 8-slot XOR within each 64-s group)
    const int sc0 = sq * 32 + (hi << 3), sc1 = sc0 + 16;
    const int ps0 = (sc0 & ~63) | ((sc0 & 63) ^ rsw);
    const int ps1 = (sc1 & ~63) | ((sc1 & 63) ^ rsw);

    for (int j = 0; j < 16; ++j) {
        const int p = j & 1;
        if (j < 15) stage(p ^ 1, j + 1);     // prefetch under compute
        __builtin_amdgcn_sched_barrier(0);

        const unsigned short* kb = &KV[p][0];
        const unsigned short* vb = &KV[p][8192];

        // this wave's 32-s quarter: 4 K reads + 4 V reads, each feeds 2 MFMAs
        bf16x8 kf[4], vf0k0, vf0k1, vf1k0, vf1k1;
#pragma unroll
        for (int kc = 0; kc < 4; ++kc)
            kf[kc] = *(const bf16x8*)(
                kb + (sq * 32 + lo5) * 64 + (((kc << 4) + (hi << 3)) ^ rsw));
        vf0k0 = *(const bf16x8*)(vb + (lo5) * 128      + ps0);
        vf0k1 = *(const bf16x8*)(vb + (lo5) * 128      + ps1);
        vf1k0 = *(const bf16x8*)(vb + (32 + lo5) * 128 + ps0);
        vf1k1 = *(const bf16x8*)(vb + (32 + lo5) * 128 + ps1);

        __builtin_amdgcn_s_setprio(1);
        f32x16 SA = ZERO16, SB = ZERO16;
#pragma unroll
        for (int kc = 0; kc < 4; ++kc)
            SA = __builtin_amdgcn_mfma_f32_32x32x16_bf16(kf[kc], qfA[kc], SA, 0, 0, 0);
#pragma unroll
        for (int kc = 0; kc < 4; ++kc)
            SB = __builtin_amdgcn_mfma_f32_32x32x16_bf16(kf[kc], qfB[kc], SB, 0, 0, 0);

        {
            float p16[16];
#pragma unroll
            for (int r = 0; r < 16; ++r) p16[r] = EXP2(SA[r]);
            unsigned w0 = cvtpk(p16[0],  p16[1]),  w1 = cvtpk(p16[2],  p16[3]);
            unsigned w2 = cvtpk(p16[4],  p16[5]),  w3 = cvtpk(p16[6],  p16[7]);
            unsigned w4 = cvtpk(p16[8],  p16[9]),  w5 = cvtpk(p16[10], p16[11]);
            unsigned w6 = cvtpk(p16[12], p16[13]), w7 = cvtpk(p16[14], p16[15]);
            plswap(w0, w2); plswap(w1, w3); plswap(w4, w6); plswap(w5, w7);
            bf16x8 pfA = __builtin_bit_cast(bf16x8, (u32x4){w0, w1, w2, w3});
            bf16x8 pfB = __builtin_bit_cast(bf16x8, (u32x4){w4, w5, w6, w7});
            accA0 = __builtin_amdgcn_mfma_f32_32x32x16_bf16(vf0k0, pfA, accA0, 0, 0, 0);
            accA0 = __builtin_amdgcn_mfma_f32_32x32x16_bf16(vf0k1, pfB, accA0, 0, 0, 0);
            accA1 = __builtin_amdgcn_mfma_f32_32x32x16_bf16(vf1k0, pfA, accA1, 0, 0, 0);
            accA1 = __builtin_amdgcn_mfma_f32_32x32x16_bf16(vf1k1, pfB, accA1, 0, 0, 0);
        }
        {
            float p16[16];
#pragma unroll
            for (int r = 0; r < 16; ++r) p16[r] = EXP2(SB[r]);
            unsigned w0 = cvtpk(p16[0],  p16[1]),  w1 = cvtpk(p16[2],  p16[3]);
            unsigned w2 = cvtpk(p16[4],  p16[5]),  w3 = cvtpk(p16[6],  p16[7]);
            unsigned w4 = cvtpk(p16[8],  p16[9]),  w5 = cvtpk(p16[10], p16[11]);
            unsigned w6 = cvtpk(p16[12], p16[13]), w7 = cvtpk(p16[14], p16[15]);
            plswap(w0, w2); plswap(w1, w3); plswap(w4, w6); plswap(w5, w7);
            bf16x8 pfA = __builtin_bit_cast(bf16x8, (u32x4){w0, w1, w2, w3});
            bf16x8 pfB = __builtin_bit_cast(bf16x8, (u32x4){w4, w5, w6, w7});
            accB0 = __builtin_amdgcn_mfma_f32_32x32x16_bf16(vf0k0, pfA, accB0, 0, 0, 0);
            accB0 = __builtin_amdgcn_mfma_f32_32x32x16_bf16(vf0k1, pfB, accB0, 0, 0, 0);
            accB1 = __builtin_amdgcn_mfma_f32_32x32x16_bf16(vf1k0, pfA, accB1, 0, 0, 0);
            accB1 = __builtin_amdgcn_mfma_f32_32x32x16_bf16(vf1k1, pfB, accB1, 0, 0, 0);
        }
        __builtin_amdgcn_s_setprio(0);

        asm volatile("s_waitcnt vmcnt(0)" ::: "memory");   // next chunk landed
        __builtin_amdgcn_s_barrier();
    }

    // ---- 4-way s-reduction, two pairwise LDS exchanges (wave-uniform) ----
    float* red = (float*)&KV[0][0];        // 64 KB reuse
    // round 1: pair w^1. even sq keep A's (give B's); odd keep B's (give A's).
    if ((w & 1) == 0) {
        *(f32x16*)(red + (size_t)w * 2048 + l * 16)        = accB0;
        *(f32x16*)(red + (size_t)w * 2048 + 1024 + l * 16) = accB1;
    } else {
        *(f32x16*)(red + (size_t)w * 2048 + l * 16)        = accA0;
        *(f32x16*)(red + (size_t)w * 2048 + 1024 + l * 16) = accA1;
    }
    __syncthreads();
    f32x16 r0 = *(const f32x16*)(red + (size_t)(w ^ 1) * 2048 + l * 16);
    f32x16 r1 = *(const f32x16*)(red + (size_t)(w ^ 1) * 2048 + 1024 + l * 16);
    f32x16 x0, x1;                         // kept quadrants, pair-summed
    if ((w & 1) == 0) { x0 = accA0 + r0; x1 = accA1 + r1; }
    else              { x0 = accB0 + r0; x1 = accB1 + r1; }
    // round 2: pair w^2. (w&2)==0 keeps chalf0 (gives x1); else keeps chalf1.
    __syncthreads();
    if ((w & 2) == 0) *(f32x16*)(red + (size_t)w * 1024 + l * 16) = x1;
    else              *(f32x16*)(red + (size_t)w * 1024 + l * 16) = x0;
    __syncthreads();
    f32x16 rr = *(const f32x16*)(red + (size_t)(w ^ 2) * 1024 + l * 16);
    f32x16 fin;
    if ((w & 2) == 0) fin = x0 + rr;
    else              fin = x1 + rr;

    // wave's final quadrant: tset = sq&1, chalf = (sq>>1)&1
    float* op = out + (size_t)(b * 512 + h * 64) * SEQ;
    const int t = t0 + tw * 64 + (sq & 1) * 32 + lo5;
    const int cbase = ((sq >> 1) & 1) * 32;
#pragma unroll
    for (int r = 0; r < 16; ++r) {
        int c = cbase + (r & 3) + 8 * (r >> 2) + 4 * hi;
        op[(size_t)c * SEQ + t] = fin[r];
    }
}

// ================================================================ fallback
// (round-1 proven path, used only if ws is too small for the bf16 buffers)

__device__ __forceinline__ bf16x8 lds_frag(const unsigned short* base, int row, int el) {
    int e = el ^ ((row & 7) << 3);
    return *(const bf16x8*)(base + row * 64 + e);
}

__global__ __launch_bounds__(256) void qkv_stats_kernel(
    const float* __restrict__ qkv, float* __restrict__ m_ws, float* __restrict__ rl_ws)
{
    __shared__ __attribute__((aligned(16))) unsigned short Kl[128 * 64];
    __shared__ __attribute__((aligned(16))) unsigned short Ql[64 * 64];
    const int head = blockIdx.x >> 4, stile = blockIdx.x & 15, s0 = stile * 128;
    const int b = head >> 3, h = head & 7;
    const float* qp = qkv + (size_t)(b * 1536 + h * 192) * SEQ;
    const float* kp = qp + (size_t)CHD * SEQ;
    const int tid = threadIdx.x, w = tid >> 6, l = tid & 63, lg = l >> 4, lr = l & 15;
    for (int idx = tid; idx < 128 * 64; idx += 256) {
        int s = idx & 127, c = idx >> 7;
        Kl[s * 64 + (c ^ ((s & 7) << 3))] = f2bf(kp[(size_t)c * SEQ + s0 + s]);
    }
    float m_run[2] = {-__builtin_inff(), -__builtin_inff()};
    float l_run[2] = {0.f, 0.f};
    for (int chunk = 0; chunk < 32; ++chunk) {
        const int t0 = chunk * 64;
        __syncthreads();
        for (int idx = tid; idx < 64 * 64; idx += 256) {
            int t = idx & 63, c = idx >> 6;
            Ql[t * 64 + (c ^ ((t & 7) << 3))] = f2bf(qp[(size_t)c * SEQ + t0 + t]);
        }
        __syncthreads();
#pragma unroll
        for (int ntl = 0; ntl < 2; ++ntl) {
            const int srow = 16 * (2 * w + ntl) + lr;
            float vals[16];
#pragma unroll
            for (int mt = 0; mt < 4; ++mt) {
                f32x4 sacc = {0.f, 0.f, 0.f, 0.f};
#pragma unroll
                for (int kk = 0; kk < 2; ++kk) {
                    bf16x8 a  = lds_frag(Ql, 16 * mt + lr, 32 * kk + 8 * lg);
                    bf16x8 bk = lds_frag(Kl, srow,         32 * kk + 8 * lg);
                    sacc = __builtin_amdgcn_mfma_f32_16x16x32_bf16(a, bk, sacc, 0, 0, 0);
                }
#pragma unroll
                for (int j = 0; j < 4; ++j) vals[mt * 4 + j] = sacc[j] * 0.125f;
            }
            float cm = vals[0];
#pragma unroll
            for (int i = 1; i < 16; ++i) cm = fmaxf(cm, vals[i]);
            cm = fmaxf(cm, __shfl_xor(cm, 16));
            cm = fmaxf(cm, __shfl_xor(cm, 32));
            float newm = fmaxf(m_run[ntl], cm);
            l_run[ntl] *= __expf(m_run[ntl] - newm);
            m_run[ntl] = newm;
            float ps = 0.f;
#pragma unroll
            for (int i = 0; i < 16; ++i) ps += __expf(vals[i] - newm);
            ps += __shfl_xor(ps, 16);
            ps += __shfl_xor(ps, 32);
            l_run[ntl] += ps;
        }
    }
    if (lg == 0) {
#pragma unroll
        for (int ntl = 0; ntl < 2; ++ntl) {
            int sg = s0 + 16 * (2 * w + ntl) + lr;
            m_ws[head * SEQ + sg]  = m_run[ntl];
            rl_ws[head * SEQ + sg] = 1.0f / l_run[ntl];
        }
    }
}

__global__ __launch_bounds__(256) void qkv_attn_kernel(
    const float* __restrict__ qkv, const float* __restrict__ m_ws,
    const float* __restrict__ rl_ws, float* __restrict__ out)
{
    __shared__ __attribute__((aligned(16))) unsigned short Ql[128 * 64];
    __shared__ __attribute__((aligned(16))) unsigned short Kl[64 * 64];
    __shared__ __attribute__((aligned(16))) unsigned short Vl[64 * 64];
    __shared__ __attribute__((aligned(16))) unsigned short Pl[128 * 64];
    const int head = blockIdx.x >> 4, ttile = blockIdx.x & 15, t0 = ttile * 128;
    const int b = head >> 3, h = head & 7;
    const float* qp  = qkv + (size_t)(b * 1536 + h * 192) * SEQ;
    const float* kp  = qp + (size_t)CHD * SEQ;
    const float* vp  = qp + (size_t)(2 * CHD) * SEQ;
    const float* mh  = m_ws  + head * SEQ;
    const float* rlh = rl_ws + head * SEQ;
    const int tid = threadIdx.x, w = tid >> 6, l = tid & 63, lg = l >> 4, lr = l & 15;
    for (int idx = tid; idx < 128 * 64; idx += 256) {
        int t = idx & 127, c = idx >> 7;
        Ql[t * 64 + (c ^ ((t & 7) << 3))] = f2bf(qp[(size_t)c * SEQ + t0 + t]);
    }
    f32x4 acc[4][2];
#pragma unroll
    for (int i = 0; i < 4; ++i)
#pragma unroll
        for (int j = 0; j < 2; ++j) acc[i][j] = (f32x4){0.f, 0.f, 0.f, 0.f};
    for (int sc = 0; sc < 32; ++sc) {
        const int s0 = sc * 64;
        __syncthreads();
        for (int idx = tid; idx < 64 * 64; idx += 256) {
            int s = idx & 63, c = idx >> 6;
            Kl[s * 64 + (c ^ ((s & 7) << 3))] = f2bf(kp[(size_t)c * SEQ + s0 + s]);
            Vl[c * 64 + (s ^ ((c & 7) << 3))] = f2bf(vp[(size_t)c * SEQ + s0 + s] * rlh[s0 + s]);
        }
        __syncthreads();
        float msv[4];
#pragma unroll
        for (int nts = 0; nts < 4; ++nts) msv[nts] = mh[s0 + 16 * nts + lr];
#pragma unroll
        for (int mts = 0; mts < 2; ++mts) {
            const int trowbase = 16 * (2 * w + mts);
#pragma unroll
            for (int nts = 0; nts < 4; ++nts) {
                f32x4 sa = {0.f, 0.f, 0.f, 0.f};
#pragma unroll
                for (int kk = 0; kk < 2; ++kk) {
                    bf16x8 a  = lds_frag(Ql, trowbase + lr, 32 * kk + 8 * lg);
                    bf16x8 bk = lds_frag(Kl, 16 * nts + lr, 32 * kk + 8 * lg);
                    sa = __builtin_amdgcn_mfma_f32_16x16x32_bf16(a, bk, sa, 0, 0, 0);
                }
                const int scol = 16 * nts + lr;
#pragma unroll
                for (int j = 0; j < 4; ++j) {
                    int trow = trowbase + 4 * lg + j;
                    float p = __expf(sa[j] * 0.125f - msv[nts]);
                    Pl[trow * 64 + (scol ^ ((trow & 7) << 3))] = f2bf(p);
                }
            }
        }
#pragma unroll
        for (int mt = 0; mt < 4; ++mt) {
#pragma unroll
            for (int ntl = 0; ntl < 2; ++ntl) {
                const int trow = 16 * (2 * w + ntl);
#pragma unroll
                for (int kk = 0; kk < 2; ++kk) {
                    bf16x8 a  = lds_frag(Vl, 16 * mt + lr, 32 * kk + 8 * lg);
                    bf16x8 bp = lds_frag(Pl, trow + lr,    32 * kk + 8 * lg);
                    acc[mt][ntl] = __builtin_amdgcn_mfma_f32_16x16x32_bf16(a, bp, acc[mt][ntl], 0, 0, 0);
                }
            }
        }
    }
    float* op = out + (size_t)(b * 512 + h * 64) * SEQ;
#pragma unroll
    for (int mt = 0; mt < 4; ++mt) {
#pragma unroll
        for (int ntl = 0; ntl < 2; ++ntl) {
            int tcol = t0 + 16 * (2 * w + ntl) + lr;
#pragma unroll
            for (int j = 0; j < 4; ++j) {
                int c = 16 * mt + 4 * lg + j;
                op[(size_t)c * SEQ + tcol] = acc[mt][ntl][j];
            }
        }
    }
}

// ================================================================ launch
extern "C" void kernel_launch(void* const* d_in, const int* in_sizes, int n_in,
                              void* d_out, int out_size, void* d_ws, size_t ws_size,
                              hipStream_t stream) {
    const float* qkv = (const float*)d_in[0];
    float* out = (float*)d_out;
    (void)in_sizes; (void)n_in; (void)out_size;

    const size_t bufE = (size_t)NHB * SEQ * CHD;           // elements per buffer
    const size_t need = 3 * bufE * 2 + (size_t)NHB * SEQ * 4;  // 24 MB + l_ws
    if (ws_size >= need) {
        unsigned short* Qt = (unsigned short*)d_ws;
        unsigned short* Kt = Qt + bufE;
        unsigned short* Vb = Kt + bufE;
        float* l_ws = (float*)(Vb + bufE);
        hipMemsetAsync(l_ws, 0, (size_t)NHB * SEQ * 4, stream);
        convert_qk   <<<dim3(NHB * 16), dim3(256), 0, stream>>>(qkv, Qt, Kt);
        statsA_kernel<<<dim3(512),      dim3(512), 0, stream>>>(Qt, Kt, l_ws);
        statsB_kernel<<<dim3(256),      dim3(256), 0, stream>>>(qkv, l_ws, Vb);
        attn14_kernel<<<dim3(512),      dim3(512), 0, stream>>>(Qt, Kt, Vb, out);
    } else {
        float* m_ws  = (float*)d_ws;
        float* rl_ws = m_ws + (size_t)NHB * SEQ;
        qkv_stats_kernel<<<dim3(NHB * 16), dim3(256), 0, stream>>>(qkv, m_ws, rl_ws);
        qkv_attn_kernel <<<dim3(NHB * 16), dim3(256), 0, stream>>>(qkv, m_ws, rl_ws, out);
    }
}

// Round 18
// 97.723 us; speedup vs baseline: 2.5487x; 2.4562x over previous
//
#include <hip/hip_runtime.h>
#include <hip/hip_bf16.h>

// QKVAttention: qkv (4,1536,2048) fp32, N_HEADS=8, ch=64, 32 total heads.
// S[t,s] = (1/8) sum_c q[c,t] k[c,s]; P = softmax over t (COLUMN softmax);
// a[c,t] = sum_s P[t,s] v[c,s].
//
//  K1 convert : Qt[h][t][c], Kt[h][s][c] bf16, transposed, XOR-pre-swizzled.
//  K2 statsA  : grid 512 (head x s-256 x T-HALF), true 2 blocks/CU (1 live
//               f32x16 -> fits 128-reg cap); unsafeAtomicAdd partials into
//               zeroed l_ws.
//  K3 statsB  : V-scale: Vb = bf16(V/l), 8-slot XOR per 64-s group.
//  K4 attn9x  : R8's attn9 (proven: VGPR 60, no spill) + native EXP2.
//               grid 512 = head x 16 t-tiles(128 t); 8 waves = 4 t-subs x
//               2 s-halves; 64-s chunks, 3 LDS bufs (48 KB), 1 barrier/chunk,
//               vmcnt(2); halved LDS reads; in-block s-pair reduction.
//               Register demand ~92 <= 128 -> REAL 2 blocks/CU (R17 lesson:
//               launch_bounds can't force occupancy past register demand).
//  EXP FIX    : __ocml_native_exp2_f32 (bare v_exp_f32).

#define SEQ   2048
#define CHD   64
#define NHB   32
#define SCALE_QK 0.42466090f   // sqrt(0.125 * log2(e))

typedef short bf16x8 __attribute__((ext_vector_type(8)));
typedef float f32x4  __attribute__((ext_vector_type(4)));
typedef float f32x16 __attribute__((ext_vector_type(16)));
typedef unsigned int   u32x4 __attribute__((ext_vector_type(4)));
typedef unsigned short us8   __attribute__((ext_vector_type(8)));

extern "C" __device__ float __ocml_native_exp2_f32(float);   // bare v_exp_f32
#define EXP2(x) __ocml_native_exp2_f32(x)

__device__ __forceinline__ unsigned short f2bf(float f) {
    unsigned int u = __builtin_bit_cast(unsigned int, f);
    u += 0x7FFFu + ((u >> 16) & 1u);   // RNE
    return (unsigned short)(u >> 16);
}

__device__ __forceinline__ void gl_lds16(const void* g, void* l) {
    __builtin_amdgcn_global_load_lds(
        (const __attribute__((address_space(1))) void*)g,
        (__attribute__((address_space(3))) void*)l, 16, 0, 0);
}

__device__ __forceinline__ unsigned cvtpk(float a, float b) {
    unsigned r;
    asm("v_cvt_pk_bf16_f32 %0, %1, %2" : "=v"(r) : "v"(a), "v"(b));
    return r;
}
__device__ __forceinline__ void plswap(unsigned &a, unsigned &b) {
    asm("v_permlane32_swap_b32 %0, %1" : "+v"(a), "+v"(b));
}

#define ZERO16 {0.f,0.f,0.f,0.f,0.f,0.f,0.f,0.f,0.f,0.f,0.f,0.f,0.f,0.f,0.f,0.f}

// ------------------------------------------------ K1: transpose+convert Q,K
__global__ __launch_bounds__(256) void convert_qk(
    const float* __restrict__ qkv, unsigned short* __restrict__ Qt,
    unsigned short* __restrict__ Kt)
{
    __shared__ float Tl[64][129];
    const int bid = blockIdx.x;
    const int head = bid >> 4, t0 = (bid & 15) * 128;
    const int b = head >> 3, h = head & 7;
    const float* base = qkv + (size_t)(b * 1536 + h * 192) * SEQ;
    const int tid = threadIdx.x;
#pragma unroll
    for (int pp = 0; pp < 2; ++pp) {
        const float* src = base + (size_t)(pp ? CHD : 0) * SEQ;
        unsigned short* dst = (pp ? Kt : Qt) + (size_t)head * SEQ * CHD;
        if (pp) __syncthreads();
        for (int e = tid; e < 8192; e += 256) {
            int c = e >> 7, ti = e & 127;
            Tl[c][ti] = src[(size_t)c * SEQ + t0 + ti];
        }
        __syncthreads();
        for (int g = tid; g < 1024; g += 256) {
            int t = g >> 3, cg = g & 7;
            us8 u;
#pragma unroll
            for (int j = 0; j < 8; ++j) u[j] = f2bf(Tl[cg * 8 + j][t] * SCALE_QK);
            *(us8*)(dst + (size_t)(t0 + t) * 64 + ((cg * 8) ^ ((t & 7) << 3))) = u;
        }
    }
}

// ------------------------------------------------ K2: partial column sums
__global__ __launch_bounds__(512, 4) void statsA_kernel(
    const unsigned short* __restrict__ Qt, const unsigned short* __restrict__ Kt,
    float* __restrict__ l_ws)
{
    __shared__ __attribute__((aligned(16))) unsigned short Qs[4][4096]; // 32 KB
    const int bid = blockIdx.x;
    const int bs  = ((bid & 7) << 6) | (bid >> 3);   // XCD swizzle (512%8==0)
    const int head = bs >> 4, s0 = ((bs >> 1) & 7) * 256, tH = bs & 1;
    const char* Qhb = (const char*)(Qt + (size_t)head * SEQ * CHD);
    const unsigned short* Kh = Kt + (size_t)head * SEQ * CHD;
    const int tid = threadIdx.x, w = tid >> 6, l = tid & 63, lo5 = l & 31, hi = l >> 5;
    const int rsw = (lo5 & 7) << 3;

    bf16x8 kfr[4];
#pragma unroll
    for (int kc = 0; kc < 4; ++kc)
        kfr[kc] = *(const bf16x8*)(
            Kh + (size_t)(s0 + w * 32 + lo5) * 64 + (((kc << 4) + (hi << 3)) ^ rsw));

    auto stage = [&](int p, int tc) {
        gl_lds16(Qhb + (size_t)(tH * 16 + tc) * 8192 + tid * 16, &Qs[p][0] + tid * 8);
    };

    float lacc[4] = {0.f, 0.f, 0.f, 0.f};

    stage(0, 0);
    stage(1, 1);
    for (int tc = 0; tc < 16; ++tc) {
        if (tc < 15) asm volatile("s_waitcnt vmcnt(1)" ::: "memory");
        else         asm volatile("s_waitcnt vmcnt(0)" ::: "memory");
        __builtin_amdgcn_s_barrier();
        __builtin_amdgcn_sched_barrier(0);
        if (tc < 14) stage((tc + 2) & 3, tc + 2);
        const unsigned short* qs = &Qs[tc & 3][0];
        __builtin_amdgcn_s_setprio(1);
#pragma unroll
        for (int ts = 0; ts < 2; ++ts) {
            f32x16 s = ZERO16;
#pragma unroll
            for (int kc = 0; kc < 4; ++kc) {
                bf16x8 qa = *(const bf16x8*)(
                    qs + (ts * 32 + lo5) * 64 + (((kc << 4) + (hi << 3)) ^ rsw));
                s = __builtin_amdgcn_mfma_f32_32x32x16_bf16(qa, kfr[kc], s, 0, 0, 0);
            }
#pragma unroll
            for (int r = 0; r < 16; ++r) lacc[r & 3] += EXP2(s[r]);
        }
        __builtin_amdgcn_s_setprio(0);
    }

    float lsum = (lacc[0] + lacc[1]) + (lacc[2] + lacc[3]);
    lsum += __shfl_xor(lsum, 32);
    if (l < 32) unsafeAtomicAdd(&l_ws[head * SEQ + s0 + w * 32 + lo5], lsum);
}

// ------------------------------------------------ K3: V-scale (memory-bound)
__global__ __launch_bounds__(256) void statsB_kernel(
    const float* __restrict__ qkv, const float* __restrict__ l_ws,
    unsigned short* __restrict__ Vb)
{
    __shared__ float rlb[256];
    const int bid = blockIdx.x;
    const int bs  = ((bid & 7) << 5) | (bid >> 3);   // XCD swizzle (256%8==0)
    const int head = bs >> 3, s0 = (bs & 7) * 256;
    const int b = head >> 3, h = head & 7;
    const int tid = threadIdx.x;

    rlb[tid] = 1.0f / l_ws[head * SEQ + s0 + tid];
    __syncthreads();

    const float* vp = qkv + (size_t)(b * 1536 + h * 192 + 2 * CHD) * SEQ;
    unsigned short* Vh = Vb + (size_t)head * SEQ * CHD;   // layout [c][2048]
    for (int g = tid; g < 2048; g += 256) {
        int c = g >> 5, si8 = (g & 31) * 8;
        const float* vrow = vp + (size_t)c * SEQ + s0 + si8;
        f32x4 v0 = *(const f32x4*)(vrow);
        f32x4 v1 = *(const f32x4*)(vrow + 4);
        us8 u;
#pragma unroll
        for (int j = 0; j < 4; ++j) u[j]     = f2bf(v0[j] * rlb[si8 + j]);
#pragma unroll
        for (int j = 0; j < 4; ++j) u[4 + j] = f2bf(v1[j] * rlb[si8 + 4 + j]);
        int swb = (si8 & ~63) | ((si8 & 63) ^ ((c & 7) << 3));
        *(us8*)(Vh + (size_t)c * SEQ + s0 + swb) = u;
    }
}

// ------------------------------------------------ K4: attention (attn9 + EXP2)
// 512 thr / 8 waves = 4 t-subtiles x 2 s-halves; block = 128 t, all 2048 s.
// 3 LDS buffers, 1 barrier/chunk, counted vmcnt(2). VGPR ~60 -> 2 blocks/CU.
__global__ __launch_bounds__(512, 4) void attn9x_kernel(
    const unsigned short* __restrict__ Qt, const unsigned short* __restrict__ Kt,
    const unsigned short* __restrict__ Vb, float* __restrict__ out)
{
    __shared__ __attribute__((aligned(16))) unsigned short KV[3][8192]; // 48 KB
    const int bid = blockIdx.x;
    const int bs  = ((bid & 7) << 6) | (bid >> 3);   // XCD swizzle (512%8==0)
    const int head = bs >> 4, t0 = (bs & 15) * 128;
    const int b = head >> 3, h = head & 7;
    const int tid = threadIdx.x, w = tid >> 6, l = tid & 63, lo5 = l & 31, hi = l >> 5;
    const int tsub = w >> 1, sh = w & 1;
    const int rsw = (lo5 & 7) << 3;
    const unsigned short* Qh = Qt + (size_t)head * SEQ * CHD;
    const char* Khb = (const char*)(Kt + (size_t)head * SEQ * CHD);
    const char* Vhb = (const char*)(Vb + (size_t)head * SEQ * CHD);
    const int tmine = t0 + tsub * 32 + lo5;

    // Q B-fragments for this wave's 32 t, register-resident
    bf16x8 qf[4];
#pragma unroll
    for (int kc = 0; kc < 4; ++kc)
        qf[kc] = *(const bf16x8*)(Qh + (size_t)tmine * 64 + (((kc << 4) + (hi << 3)) ^ rsw));

    f32x16 acc[2] = {ZERO16, ZERO16};   // [c-half], partial over this sh's s

    // stage 64-s chunk cj into buffer p: K 8 KB + V 8 KB; 1 load each/thread.
    const int vc = tid >> 3, vs16 = (tid & 7) * 16;
    auto stage = [&](int p, int cj) {
        unsigned short* kb = &KV[p][0];
        unsigned short* vb = &KV[p][4096];
        gl_lds16(Khb + (size_t)cj * 8192 + tid * 16, kb + tid * 8);
        gl_lds16(Vhb + (size_t)vc * 4096 + (size_t)cj * 128 + vs16, vb + tid * 8);
    };

    stage(0, 0);
    stage(1, 1);

    for (int j = 0; j < 32; ++j) {
        const int p = j % 3;
        if (j < 31) asm volatile("s_waitcnt vmcnt(2)" ::: "memory");
        else        asm volatile("s_waitcnt vmcnt(0)" ::: "memory");
        __builtin_amdgcn_s_barrier();          // everyone's chunk-j loads done
        __builtin_amdgcn_sched_barrier(0);
        if (j < 30) stage((j + 2) % 3, j + 2); // overwrites buf read in iter j-1

        const unsigned short* kb = &KV[p][0];
        const unsigned short* vb = &KV[p][4096];
        // this wave's 32-s half only: K rows sh*32+lo5, V cols sh*32..+31
        bf16x8 kf[4], vf[4];
#pragma unroll
        for (int kc = 0; kc < 4; ++kc)
            kf[kc] = *(const bf16x8*)(
                kb + (sh * 32 + lo5) * 64 + (((kc << 4) + (hi << 3)) ^ rsw));
#pragma unroll
        for (int ct = 0; ct < 2; ++ct)
#pragma unroll
            for (int ks = 0; ks < 2; ++ks)
                vf[ct * 2 + ks] = *(const bf16x8*)(
                    vb + (ct * 32 + lo5) * 64 +
                    (((sh * 32 + ks * 16 + (hi << 3))) ^ rsw));

        __builtin_amdgcn_s_setprio(1);
        f32x16 sacc = ZERO16;
#pragma unroll
        for (int kc = 0; kc < 4; ++kc)
            sacc = __builtin_amdgcn_mfma_f32_32x32x16_bf16(kf[kc], qf[kc], sacc, 0, 0, 0);
        float p16[16];
#pragma unroll
        for (int r = 0; r < 16; ++r) p16[r] = EXP2(sacc[r]);
        unsigned w0 = cvtpk(p16[0],  p16[1]),  w1 = cvtpk(p16[2],  p16[3]);
        unsigned w2 = cvtpk(p16[4],  p16[5]),  w3 = cvtpk(p16[6],  p16[7]);
        unsigned w4 = cvtpk(p16[8],  p16[9]),  w5 = cvtpk(p16[10], p16[11]);
        unsigned w6 = cvtpk(p16[12], p16[13]), w7 = cvtpk(p16[14], p16[15]);
        plswap(w0, w2); plswap(w1, w3); plswap(w4, w6); plswap(w5, w7);
        bf16x8 pfA = __builtin_bit_cast(bf16x8, (u32x4){w0, w1, w2, w3});
        bf16x8 pfB = __builtin_bit_cast(bf16x8, (u32x4){w4, w5, w6, w7});
#pragma unroll
        for (int ct = 0; ct < 2; ++ct) {
            acc[ct] = __builtin_amdgcn_mfma_f32_32x32x16_bf16(vf[ct * 2 + 0], pfA, acc[ct], 0, 0, 0);
            acc[ct] = __builtin_amdgcn_mfma_f32_32x32x16_bf16(vf[ct * 2 + 1], pfB, acc[ct], 0, 0, 0);
        }
        __builtin_amdgcn_s_setprio(0);
    }

    // ---- s-pair exchange (partner = same tsub, other s-half)
    __syncthreads();                       // all buffer reads done before reuse
    float* red = (float*)&KV[0][0];        // 32 KB reuse
    *(f32x16*)(red + (size_t)w * 1024 + l * 16) = acc[sh ^ 1];
    __syncthreads();
    f32x16 peer = *(const f32x16*)(red + (size_t)(w ^ 1) * 1024 + l * 16);
    f32x16 fin = acc[sh] + peer;

    float* op = out + (size_t)(b * 512 + h * 64) * SEQ;
#pragma unroll
    for (int r = 0; r < 16; ++r) {
        int c = sh * 32 + (r & 3) + 8 * (r >> 2) + 4 * hi;
        op[(size_t)c * SEQ + tmine] = fin[r];
    }
}

// ================================================================ fallback
// (round-1 proven path, used only if ws is too small for the bf16 buffers)

__device__ __forceinline__ bf16x8 lds_frag(const unsigned short* base, int row, int el) {
    int e = el ^ ((row & 7) << 3);
    return *(const bf16x8*)(base + row * 64 + e);
}

__global__ __launch_bounds__(256) void qkv_stats_kernel(
    const float* __restrict__ qkv, float* __restrict__ m_ws, float* __restrict__ rl_ws)
{
    __shared__ __attribute__((aligned(16))) unsigned short Kl[128 * 64];
    __shared__ __attribute__((aligned(16))) unsigned short Ql[64 * 64];
    const int head = blockIdx.x >> 4, stile = blockIdx.x & 15, s0 = stile * 128;
    const int b = head >> 3, h = head & 7;
    const float* qp = qkv + (size_t)(b * 1536 + h * 192) * SEQ;
    const float* kp = qp + (size_t)CHD * SEQ;
    const int tid = threadIdx.x, w = tid >> 6, l = tid & 63, lg = l >> 4, lr = l & 15;
    for (int idx = tid; idx < 128 * 64; idx += 256) {
        int s = idx & 127, c = idx >> 7;
        Kl[s * 64 + (c ^ ((s & 7) << 3))] = f2bf(kp[(size_t)c * SEQ + s0 + s]);
    }
    float m_run[2] = {-__builtin_inff(), -__builtin_inff()};
    float l_run[2] = {0.f, 0.f};
    for (int chunk = 0; chunk < 32; ++chunk) {
        const int t0 = chunk * 64;
        __syncthreads();
        for (int idx = tid; idx < 64 * 64; idx += 256) {
            int t = idx & 63, c = idx >> 6;
            Ql[t * 64 + (c ^ ((t & 7) << 3))] = f2bf(qp[(size_t)c * SEQ + t0 + t]);
        }
        __syncthreads();
#pragma unroll
        for (int ntl = 0; ntl < 2; ++ntl) {
            const int srow = 16 * (2 * w + ntl) + lr;
            float vals[16];
#pragma unroll
            for (int mt = 0; mt < 4; ++mt) {
                f32x4 sacc = {0.f, 0.f, 0.f, 0.f};
#pragma unroll
                for (int kk = 0; kk < 2; ++kk) {
                    bf16x8 a  = lds_frag(Ql, 16 * mt + lr, 32 * kk + 8 * lg);
                    bf16x8 bk = lds_frag(Kl, srow,         32 * kk + 8 * lg);
                    sacc = __builtin_amdgcn_mfma_f32_16x16x32_bf16(a, bk, sacc, 0, 0, 0);
                }
#pragma unroll
                for (int j = 0; j < 4; ++j) vals[mt * 4 + j] = sacc[j] * 0.125f;
            }
            float cm = vals[0];
#pragma unroll
            for (int i = 1; i < 16; ++i) cm = fmaxf(cm, vals[i]);
            cm = fmaxf(cm, __shfl_xor(cm, 16));
            cm = fmaxf(cm, __shfl_xor(cm, 32));
            float newm = fmaxf(m_run[ntl], cm);
            l_run[ntl] *= __expf(m_run[ntl] - newm);
            m_run[ntl] = newm;
            float ps = 0.f;
#pragma unroll
            for (int i = 0; i < 16; ++i) ps += __expf(vals[i] - newm);
            ps += __shfl_xor(ps, 16);
            ps += __shfl_xor(ps, 32);
            l_run[ntl] += ps;
        }
    }
    if (lg == 0) {
#pragma unroll
        for (int ntl = 0; ntl < 2; ++ntl) {
            int sg = s0 + 16 * (2 * w + ntl) + lr;
            m_ws[head * SEQ + sg]  = m_run[ntl];
            rl_ws[head * SEQ + sg] = 1.0f / l_run[ntl];
        }
    }
}

__global__ __launch_bounds__(256) void qkv_attn_kernel(
    const float* __restrict__ qkv, const float* __restrict__ m_ws,
    const float* __restrict__ rl_ws, float* __restrict__ out)
{
    __shared__ __attribute__((aligned(16))) unsigned short Ql[128 * 64];
    __shared__ __attribute__((aligned(16))) unsigned short Kl[64 * 64];
    __shared__ __attribute__((aligned(16))) unsigned short Vl[64 * 64];
    __shared__ __attribute__((aligned(16))) unsigned short Pl[128 * 64];
    const int head = blockIdx.x >> 4, ttile = blockIdx.x & 15, t0 = ttile * 128;
    const int b = head >> 3, h = head & 7;
    const float* qp  = qkv + (size_t)(b * 1536 + h * 192) * SEQ;
    const float* kp  = qp + (size_t)CHD * SEQ;
    const float* vp  = qp + (size_t)(2 * CHD) * SEQ;
    const float* mh  = m_ws  + head * SEQ;
    const float* rlh = rl_ws + head * SEQ;
    const int tid = threadIdx.x, w = tid >> 6, l = tid & 63, lg = l >> 4, lr = l & 15;
    for (int idx = tid; idx < 128 * 64; idx += 256) {
        int t = idx & 127, c = idx >> 7;
        Ql[t * 64 + (c ^ ((t & 7) << 3))] = f2bf(qp[(size_t)c * SEQ + t0 + t]);
    }
    f32x4 acc[4][2];
#pragma unroll
    for (int i = 0; i < 4; ++i)
#pragma unroll
        for (int j = 0; j < 2; ++j) acc[i][j] = (f32x4){0.f, 0.f, 0.f, 0.f};
    for (int sc = 0; sc < 32; ++sc) {
        const int s0 = sc * 64;
        __syncthreads();
        for (int idx = tid; idx < 64 * 64; idx += 256) {
            int s = idx & 63, c = idx >> 6;
            Kl[s * 64 + (c ^ ((s & 7) << 3))] = f2bf(kp[(size_t)c * SEQ + s0 + s]);
            Vl[c * 64 + (s ^ ((c & 7) << 3))] = f2bf(vp[(size_t)c * SEQ + s0 + s] * rlh[s0 + s]);
        }
        __syncthreads();
        float msv[4];
#pragma unroll
        for (int nts = 0; nts < 4; ++nts) msv[nts] = mh[s0 + 16 * nts + lr];
#pragma unroll
        for (int mts = 0; mts < 2; ++mts) {
            const int trowbase = 16 * (2 * w + mts);
#pragma unroll
            for (int nts = 0; nts < 4; ++nts) {
                f32x4 sa = {0.f, 0.f, 0.f, 0.f};
#pragma unroll
                for (int kk = 0; kk < 2; ++kk) {
                    bf16x8 a  = lds_frag(Ql, trowbase + lr, 32 * kk + 8 * lg);
                    bf16x8 bk = lds_frag(Kl, 16 * nts + lr, 32 * kk + 8 * lg);
                    sa = __builtin_amdgcn_mfma_f32_16x16x32_bf16(a, bk, sa, 0, 0, 0);
                }
                const int scol = 16 * nts + lr;
#pragma unroll
                for (int j = 0; j < 4; ++j) {
                    int trow = trowbase + 4 * lg + j;
                    float p = __expf(sa[j] * 0.125f - msv[nts]);
                    Pl[trow * 64 + (scol ^ ((trow & 7) << 3))] = f2bf(p);
                }
            }
        }
#pragma unroll
        for (int mt = 0; mt < 4; ++mt) {
#pragma unroll
            for (int ntl = 0; ntl < 2; ++ntl) {
                const int trow = 16 * (2 * w + ntl);
#pragma unroll
                for (int kk = 0; kk < 2; ++kk) {
                    bf16x8 a  = lds_frag(Vl, 16 * mt + lr, 32 * kk + 8 * lg);
                    bf16x8 bp = lds_frag(Pl, trow + lr,    32 * kk + 8 * lg);
                    acc[mt][ntl] = __builtin_amdgcn_mfma_f32_16x16x32_bf16(a, bp, acc[mt][ntl], 0, 0, 0);
                }
            }
        }
    }
    float* op = out + (size_t)(b * 512 + h * 64) * SEQ;
#pragma unroll
    for (int mt = 0; mt < 4; ++mt) {
#pragma unroll
        for (int ntl = 0; ntl < 2; ++ntl) {
            int tcol = t0 + 16 * (2 * w + ntl) + lr;
#pragma unroll
            for (int j = 0; j < 4; ++j) {
                int c = 16 * mt + 4 * lg + j;
                op[(size_t)c * SEQ + tcol] = acc[mt][ntl][j];
            }
        }
    }
}

// ================================================================ launch
extern "C" void kernel_launch(void* const* d_in, const int* in_sizes, int n_in,
                              void* d_out, int out_size, void* d_ws, size_t ws_size,
                              hipStream_t stream) {
    const float* qkv = (const float*)d_in[0];
    float* out = (float*)d_out;
    (void)in_sizes; (void)n_in; (void)out_size;

    const size_t bufE = (size_t)NHB * SEQ * CHD;           // elements per buffer
    const size_t need = 3 * bufE * 2 + (size_t)NHB * SEQ * 4;  // 24 MB + l_ws
    if (ws_size >= need) {
        unsigned short* Qt = (unsigned short*)d_ws;
        unsigned short* Kt = Qt + bufE;
        unsigned short* Vb = Kt + bufE;
        float* l_ws = (float*)(Vb + bufE);
        hipMemsetAsync(l_ws, 0, (size_t)NHB * SEQ * 4, stream);
        convert_qk   <<<dim3(NHB * 16), dim3(256), 0, stream>>>(qkv, Qt, Kt);
        statsA_kernel<<<dim3(512),      dim3(512), 0, stream>>>(Qt, Kt, l_ws);
        statsB_kernel<<<dim3(256),      dim3(256), 0, stream>>>(qkv, l_ws, Vb);
        attn9x_kernel<<<dim3(NHB * 16), dim3(512), 0, stream>>>(Qt, Kt, Vb, out);
    } else {
        float* m_ws  = (float*)d_ws;
        float* rl_ws = m_ws + (size_t)NHB * SEQ;
        qkv_stats_kernel<<<dim3(NHB * 16), dim3(256), 0, stream>>>(qkv, m_ws, rl_ws);
        qkv_attn_kernel <<<dim3(NHB * 16), dim3(256), 0, stream>>>(qkv, m_ws, rl_ws, out);
    }
}

// Round 20
// 82.489 us; speedup vs baseline: 3.0194x; 1.1847x over previous
//
#include <hip/hip_runtime.h>
#include <hip/hip_bf16.h>

// QKVAttention: qkv (4,1536,2048) fp32, N_HEADS=8, ch=64, 32 total heads.
// S[t,s] = (1/8) sum_c q[c,t] k[c,s]; P = softmax over t (COLUMN softmax);
// a[c,t] = sum_s P[t,s] v[c,s].
//
//  VERIFIED BEST (R14, 83.85 us, absmax 1.95e-3) — byte-for-byte revert.
//  K1 convert : Qt[h][t][c], Kt[h][s][c] bf16, transposed, XOR-pre-swizzled,
//               scale sqrt(0.125*log2e) baked in (so exp(S) == exp2(S')).
//  K2 stats10 : block = 256 s (8 waves x 32 s, K in regs), 64-t chunks of
//               shared Q staged into 4 LDS buffers, vmcnt(1), 1 barrier.
//  K3 attn13  : attn8 staging + 2:1 MFMA:LDS-read. 8 waves = 4 t-sub(64t,
//               2 reg Q-sets) x 2 s-halves; each wave reads only its 32-s
//               half of K/V; every fragment feeds 2 MFMAs. Named
//               accumulators + wave-uniform branches. s-pair LDS epilogue.
//  EXP FIX    : __ocml_native_exp2_f32 (bare v_exp_f32) — R12's 40-us win.
//  R19 lesson : 4-way QK chain-split miscompiled (absmax 7.4e-2) — the
//               2-barrier/vmcnt ledger is fragile under register-pressure
//               rescheduling; do not graft ILP transforms onto it blind.

#define SEQ   2048
#define CHD   64
#define NHB   32
#define SCALE_QK 0.42466090f   // sqrt(0.125 * log2(e))

typedef short bf16x8 __attribute__((ext_vector_type(8)));
typedef float f32x4  __attribute__((ext_vector_type(4)));
typedef float f32x16 __attribute__((ext_vector_type(16)));
typedef unsigned int   u32x4 __attribute__((ext_vector_type(4)));
typedef unsigned short us8   __attribute__((ext_vector_type(8)));

extern "C" __device__ float __ocml_native_exp2_f32(float);   // bare v_exp_f32
#define EXP2(x) __ocml_native_exp2_f32(x)

__device__ __forceinline__ unsigned short f2bf(float f) {
    unsigned int u = __builtin_bit_cast(unsigned int, f);
    u += 0x7FFFu + ((u >> 16) & 1u);   // RNE
    return (unsigned short)(u >> 16);
}

__device__ __forceinline__ void gl_lds16(const void* g, void* l) {
    __builtin_amdgcn_global_load_lds(
        (const __attribute__((address_space(1))) void*)g,
        (__attribute__((address_space(3))) void*)l, 16, 0, 0);
}

__device__ __forceinline__ unsigned cvtpk(float a, float b) {
    unsigned r;
    asm("v_cvt_pk_bf16_f32 %0, %1, %2" : "=v"(r) : "v"(a), "v"(b));
    return r;
}
__device__ __forceinline__ void plswap(unsigned &a, unsigned &b) {
    asm("v_permlane32_swap_b32 %0, %1" : "+v"(a), "+v"(b));
}

#define ZERO16 {0.f,0.f,0.f,0.f,0.f,0.f,0.f,0.f,0.f,0.f,0.f,0.f,0.f,0.f,0.f,0.f}

// ------------------------------------------------ K1: transpose+convert Q,K
__global__ __launch_bounds__(256) void convert_qk(
    const float* __restrict__ qkv, unsigned short* __restrict__ Qt,
    unsigned short* __restrict__ Kt)
{
    __shared__ float Tl[64][129];
    const int bid = blockIdx.x;
    const int head = bid >> 4, t0 = (bid & 15) * 128;
    const int b = head >> 3, h = head & 7;
    const float* base = qkv + (size_t)(b * 1536 + h * 192) * SEQ;
    const int tid = threadIdx.x;
#pragma unroll
    for (int pp = 0; pp < 2; ++pp) {
        const float* src = base + (size_t)(pp ? CHD : 0) * SEQ;
        unsigned short* dst = (pp ? Kt : Qt) + (size_t)head * SEQ * CHD;
        if (pp) __syncthreads();
        for (int e = tid; e < 8192; e += 256) {
            int c = e >> 7, ti = e & 127;
            Tl[c][ti] = src[(size_t)c * SEQ + t0 + ti];
        }
        __syncthreads();
        for (int g = tid; g < 1024; g += 256) {
            int t = g >> 3, cg = g & 7;
            us8 u;
#pragma unroll
            for (int j = 0; j < 8; ++j) u[j] = f2bf(Tl[cg * 8 + j][t] * SCALE_QK);
            *(us8*)(dst + (size_t)(t0 + t) * 64 + ((cg * 8) ^ ((t & 7) << 3))) = u;
        }
    }
}

// ------------------------------------------------ K2: column sums + V scale
// block = 256 s (8 waves x 32 s); loop 64-t chunks of shared Q in LDS.
__global__ __launch_bounds__(512, 2) void stats10_kernel(
    const float* __restrict__ qkv, const unsigned short* __restrict__ Qt,
    const unsigned short* __restrict__ Kt, unsigned short* __restrict__ Vb)
{
    __shared__ __attribute__((aligned(16))) unsigned short Qs[4][4096]; // 32 KB
    __shared__ float rlb[256];
    const int bid = blockIdx.x;
    const int bs  = ((bid & 7) << 5) | (bid >> 3);   // XCD swizzle (256%8==0)
    const int head = bs >> 3, s0 = (bs & 7) * 256;
    const int b = head >> 3, h = head & 7;
    const char* Qhb = (const char*)(Qt + (size_t)head * SEQ * CHD);
    const unsigned short* Kh = Kt + (size_t)head * SEQ * CHD;
    const int tid = threadIdx.x, w = tid >> 6, l = tid & 63, lo5 = l & 31, hi = l >> 5;
    const int rsw = (lo5 & 7) << 3;

    // this wave's 32 s, K register-resident
    bf16x8 kfr[4];
#pragma unroll
    for (int kc = 0; kc < 4; ++kc)
        kfr[kc] = *(const bf16x8*)(
            Kh + (size_t)(s0 + w * 32 + lo5) * 64 + (((kc << 4) + (hi << 3)) ^ rsw));

    auto stage = [&](int p, int tc) {
        gl_lds16(Qhb + (size_t)tc * 8192 + tid * 16, &Qs[p][0] + tid * 8);
    };

    float lacc[4] = {0.f, 0.f, 0.f, 0.f};

    stage(0, 0);
    stage(1, 1);
    for (int tc = 0; tc < 32; ++tc) {
        if (tc < 31) asm volatile("s_waitcnt vmcnt(1)" ::: "memory");
        else         asm volatile("s_waitcnt vmcnt(0)" ::: "memory");
        __builtin_amdgcn_s_barrier();
        __builtin_amdgcn_sched_barrier(0);
        if (tc < 30) stage((tc + 2) & 3, tc + 2);
        const unsigned short* qs = &Qs[tc & 3][0];
        __builtin_amdgcn_s_setprio(1);
#pragma unroll
        for (int ts = 0; ts < 2; ++ts) {
            f32x16 s = ZERO16;
#pragma unroll
            for (int kc = 0; kc < 4; ++kc) {
                bf16x8 qa = *(const bf16x8*)(
                    qs + (ts * 32 + lo5) * 64 + (((kc << 4) + (hi << 3)) ^ rsw));
                s = __builtin_amdgcn_mfma_f32_32x32x16_bf16(qa, kfr[kc], s, 0, 0, 0);
            }
#pragma unroll
            for (int r = 0; r < 16; ++r) lacc[r & 3] += EXP2(s[r]);
        }
        __builtin_amdgcn_s_setprio(0);
    }

    float lsum = (lacc[0] + lacc[1]) + (lacc[2] + lacc[3]);
    lsum += __shfl_xor(lsum, 32);
    if (l < 32) rlb[w * 32 + lo5] = 1.0f / lsum;
    __syncthreads();

    // V: scale by 1/l[s], bf16, 8-slot XOR pre-swizzle within each 64-s group
    const float* vp = qkv + (size_t)(b * 1536 + h * 192 + 2 * CHD) * SEQ;
    unsigned short* Vh = Vb + (size_t)head * SEQ * CHD;   // layout [c][2048]
    for (int g = tid; g < 2048; g += 512) {
        int c = g >> 5, si8 = (g & 31) * 8;
        const float* vrow = vp + (size_t)c * SEQ + s0 + si8;
        f32x4 v0 = *(const f32x4*)(vrow);
        f32x4 v1 = *(const f32x4*)(vrow + 4);
        us8 u;
#pragma unroll
        for (int j = 0; j < 4; ++j) u[j]     = f2bf(v0[j] * rlb[si8 + j]);
#pragma unroll
        for (int j = 0; j < 4; ++j) u[4 + j] = f2bf(v1[j] * rlb[si8 + 4 + j]);
        int swb = (si8 & ~63) | ((si8 & 63) ^ ((c & 7) << 3));
        *(us8*)(Vh + (size_t)c * SEQ + s0 + swb) = u;
    }
}

// ------------------------------------------------ K3: attention (2:1 LDS)
// 512 thr / 8 waves = 4 t-sub(64t) x 2 s-halves; block = 256 t, all s.
// attn8 staging: 64-s chunks, 4 LDS bufs, 1 barrier/chunk, vmcnt(2).
__global__ __launch_bounds__(512, 1) void attn13_kernel(
    const unsigned short* __restrict__ Qt, const unsigned short* __restrict__ Kt,
    const unsigned short* __restrict__ Vb, float* __restrict__ out)
{
    __shared__ __attribute__((aligned(16))) unsigned short KV[4][8192]; // 64 KB
    const int bid = blockIdx.x;
    const int bs  = ((bid & 7) << 5) | (bid >> 3);   // XCD swizzle (256%8==0)
    const int head = bs >> 3, t0 = (bs & 7) * 256;
    const int b = head >> 3, h = head & 7;
    const int tid = threadIdx.x, w = tid >> 6, l = tid & 63, lo5 = l & 31, hi = l >> 5;
    const int tw = w >> 1, sh = w & 1;
    const int rsw = (lo5 & 7) << 3;
    const unsigned short* Qh = Qt + (size_t)head * SEQ * CHD;
    const char* Khb = (const char*)(Kt + (size_t)head * SEQ * CHD);
    const char* Vhb = (const char*)(Vb + (size_t)head * SEQ * CHD);

    // Q B-fragments for this wave's 2 t-sets (64 t), register-resident
    bf16x8 qfA[4], qfB[4];
#pragma unroll
    for (int kc = 0; kc < 4; ++kc) {
        qfA[kc] = *(const bf16x8*)(
            Qh + (size_t)(t0 + tw * 64 + lo5) * 64 + (((kc << 4) + (hi << 3)) ^ rsw));
        qfB[kc] = *(const bf16x8*)(
            Qh + (size_t)(t0 + tw * 64 + 32 + lo5) * 64 + (((kc << 4) + (hi << 3)) ^ rsw));
    }

    // named accumulators: acc<tset><c-half>, partial over this wave's s-half
    f32x16 accA0 = ZERO16, accA1 = ZERO16, accB0 = ZERO16, accB1 = ZERO16;

    // stage 64-s chunk cj: K 8 KB + V 8 KB; 1 load each per thread.
    const int vc = tid >> 3, vs16 = (tid & 7) * 16;
    auto stage = [&](int p, int cj) {
        unsigned short* kb = &KV[p][0];
        unsigned short* vb = &KV[p][4096];
        gl_lds16(Khb + (size_t)cj * 8192 + tid * 16, kb + tid * 8);
        gl_lds16(Vhb + (size_t)vc * 4096 + (size_t)cj * 128 + vs16, vb + tid * 8);
    };

    stage(0, 0);
    stage(1, 1);

    for (int j = 0; j < 32; ++j) {
        const int p = j & 3;
        if (j < 31) asm volatile("s_waitcnt vmcnt(2)" ::: "memory");
        else        asm volatile("s_waitcnt vmcnt(0)" ::: "memory");
        __builtin_amdgcn_s_barrier();          // everyone's chunk-j loads done
        __builtin_amdgcn_sched_barrier(0);
        if (j < 30) stage((j + 2) & 3, j + 2); // buf was last read at j-2

        const unsigned short* kb = &KV[p][0];
        const unsigned short* vb = &KV[p][4096];

        // this wave's 32-s half only: 4 K reads + 4 V reads, each feeds 2 MFMAs
        bf16x8 kf[4], vf0k0, vf0k1, vf1k0, vf1k1;
#pragma unroll
        for (int kc = 0; kc < 4; ++kc)
            kf[kc] = *(const bf16x8*)(
                kb + (sh * 32 + lo5) * 64 + (((kc << 4) + (hi << 3)) ^ rsw));
        vf0k0 = *(const bf16x8*)(vb + (lo5) * 64       + ((sh * 32 +      (hi << 3)) ^ rsw));
        vf0k1 = *(const bf16x8*)(vb + (lo5) * 64       + ((sh * 32 + 16 + (hi << 3)) ^ rsw));
        vf1k0 = *(const bf16x8*)(vb + (32 + lo5) * 64  + ((sh * 32 +      (hi << 3)) ^ rsw));
        vf1k1 = *(const bf16x8*)(vb + (32 + lo5) * 64  + ((sh * 32 + 16 + (hi << 3)) ^ rsw));

        __builtin_amdgcn_s_setprio(1);
        // QK: S-tiles for both t-sets from the same K fragments
        f32x16 SA = ZERO16, SB = ZERO16;
#pragma unroll
        for (int kc = 0; kc < 4; ++kc)
            SA = __builtin_amdgcn_mfma_f32_32x32x16_bf16(kf[kc], qfA[kc], SA, 0, 0, 0);
#pragma unroll
        for (int kc = 0; kc < 4; ++kc)
            SB = __builtin_amdgcn_mfma_f32_32x32x16_bf16(kf[kc], qfB[kc], SB, 0, 0, 0);

        // P for t-set A
        {
            float p16[16];
#pragma unroll
            for (int r = 0; r < 16; ++r) p16[r] = EXP2(SA[r]);
            unsigned w0 = cvtpk(p16[0],  p16[1]),  w1 = cvtpk(p16[2],  p16[3]);
            unsigned w2 = cvtpk(p16[4],  p16[5]),  w3 = cvtpk(p16[6],  p16[7]);
            unsigned w4 = cvtpk(p16[8],  p16[9]),  w5 = cvtpk(p16[10], p16[11]);
            unsigned w6 = cvtpk(p16[12], p16[13]), w7 = cvtpk(p16[14], p16[15]);
            plswap(w0, w2); plswap(w1, w3); plswap(w4, w6); plswap(w5, w7);
            bf16x8 pfA = __builtin_bit_cast(bf16x8, (u32x4){w0, w1, w2, w3});
            bf16x8 pfB = __builtin_bit_cast(bf16x8, (u32x4){w4, w5, w6, w7});
            accA0 = __builtin_amdgcn_mfma_f32_32x32x16_bf16(vf0k0, pfA, accA0, 0, 0, 0);
            accA0 = __builtin_amdgcn_mfma_f32_32x32x16_bf16(vf0k1, pfB, accA0, 0, 0, 0);
            accA1 = __builtin_amdgcn_mfma_f32_32x32x16_bf16(vf1k0, pfA, accA1, 0, 0, 0);
            accA1 = __builtin_amdgcn_mfma_f32_32x32x16_bf16(vf1k1, pfB, accA1, 0, 0, 0);
        }
        // P for t-set B
        {
            float p16[16];
#pragma unroll
            for (int r = 0; r < 16; ++r) p16[r] = EXP2(SB[r]);
            unsigned w0 = cvtpk(p16[0],  p16[1]),  w1 = cvtpk(p16[2],  p16[3]);
            unsigned w2 = cvtpk(p16[4],  p16[5]),  w3 = cvtpk(p16[6],  p16[7]);
            unsigned w4 = cvtpk(p16[8],  p16[9]),  w5 = cvtpk(p16[10], p16[11]);
            unsigned w6 = cvtpk(p16[12], p16[13]), w7 = cvtpk(p16[14], p16[15]);
            plswap(w0, w2); plswap(w1, w3); plswap(w4, w6); plswap(w5, w7);
            bf16x8 pfA = __builtin_bit_cast(bf16x8, (u32x4){w0, w1, w2, w3});
            bf16x8 pfB = __builtin_bit_cast(bf16x8, (u32x4){w4, w5, w6, w7});
            accB0 = __builtin_amdgcn_mfma_f32_32x32x16_bf16(vf0k0, pfA, accB0, 0, 0, 0);
            accB0 = __builtin_amdgcn_mfma_f32_32x32x16_bf16(vf0k1, pfB, accB0, 0, 0, 0);
            accB1 = __builtin_amdgcn_mfma_f32_32x32x16_bf16(vf1k0, pfA, accB1, 0, 0, 0);
            accB1 = __builtin_amdgcn_mfma_f32_32x32x16_bf16(vf1k1, pfB, accB1, 0, 0, 0);
        }
        __builtin_amdgcn_s_setprio(0);
    }

    // ---- s-pair exchange (partner = w^1, same tw). Wave keeps c-half == sh.
    __syncthreads();                       // all KV reads done before reuse
    float* red = (float*)&KV[0][0];        // 64 KB reuse: 8 waves x 2 slots
    if (sh == 0) {                         // give away c-half 1 (both t-sets)
        *(f32x16*)(red + (size_t)w * 2048 + l * 16)        = accA1;
        *(f32x16*)(red + (size_t)w * 2048 + 1024 + l * 16) = accB1;
    } else {                               // give away c-half 0
        *(f32x16*)(red + (size_t)w * 2048 + l * 16)        = accA0;
        *(f32x16*)(red + (size_t)w * 2048 + 1024 + l * 16) = accB0;
    }
    __syncthreads();
    f32x16 pA = *(const f32x16*)(red + (size_t)(w ^ 1) * 2048 + l * 16);
    f32x16 pB = *(const f32x16*)(red + (size_t)(w ^ 1) * 2048 + 1024 + l * 16);
    f32x16 finA, finB;
    if (sh == 0) { finA = accA0 + pA; finB = accB0 + pB; }
    else         { finA = accA1 + pA; finB = accB1 + pB; }

    float* op = out + (size_t)(b * 512 + h * 64) * SEQ;
    const int tA = t0 + tw * 64 + lo5, tB = tA + 32;
#pragma unroll
    for (int r = 0; r < 16; ++r) {
        int c = sh * 32 + (r & 3) + 8 * (r >> 2) + 4 * hi;
        op[(size_t)c * SEQ + tA] = finA[r];
        op[(size_t)c * SEQ + tB] = finB[r];
    }
}

// ================================================================ fallback
// (round-1 proven path, used only if ws is too small for the bf16 buffers)

__device__ __forceinline__ bf16x8 lds_frag(const unsigned short* base, int row, int el) {
    int e = el ^ ((row & 7) << 3);
    return *(const bf16x8*)(base + row * 64 + e);
}

__global__ __launch_bounds__(256) void qkv_stats_kernel(
    const float* __restrict__ qkv, float* __restrict__ m_ws, float* __restrict__ rl_ws)
{
    __shared__ __attribute__((aligned(16))) unsigned short Kl[128 * 64];
    __shared__ __attribute__((aligned(16))) unsigned short Ql[64 * 64];
    const int head = blockIdx.x >> 4, stile = blockIdx.x & 15, s0 = stile * 128;
    const int b = head >> 3, h = head & 7;
    const float* qp = qkv + (size_t)(b * 1536 + h * 192) * SEQ;
    const float* kp = qp + (size_t)CHD * SEQ;
    const int tid = threadIdx.x, w = tid >> 6, l = tid & 63, lg = l >> 4, lr = l & 15;
    for (int idx = tid; idx < 128 * 64; idx += 256) {
        int s = idx & 127, c = idx >> 7;
        Kl[s * 64 + (c ^ ((s & 7) << 3))] = f2bf(kp[(size_t)c * SEQ + s0 + s]);
    }
    float m_run[2] = {-__builtin_inff(), -__builtin_inff()};
    float l_run[2] = {0.f, 0.f};
    for (int chunk = 0; chunk < 32; ++chunk) {
        const int t0 = chunk * 64;
        __syncthreads();
        for (int idx = tid; idx < 64 * 64; idx += 256) {
            int t = idx & 63, c = idx >> 6;
            Ql[t * 64 + (c ^ ((t & 7) << 3))] = f2bf(qp[(size_t)c * SEQ + t0 + t]);
        }
        __syncthreads();
#pragma unroll
        for (int ntl = 0; ntl < 2; ++ntl) {
            const int srow = 16 * (2 * w + ntl) + lr;
            float vals[16];
#pragma unroll
            for (int mt = 0; mt < 4; ++mt) {
                f32x4 sacc = {0.f, 0.f, 0.f, 0.f};
#pragma unroll
                for (int kk = 0; kk < 2; ++kk) {
                    bf16x8 a  = lds_frag(Ql, 16 * mt + lr, 32 * kk + 8 * lg);
                    bf16x8 bk = lds_frag(Kl, srow,         32 * kk + 8 * lg);
                    sacc = __builtin_amdgcn_mfma_f32_16x16x32_bf16(a, bk, sacc, 0, 0, 0);
                }
#pragma unroll
                for (int j = 0; j < 4; ++j) vals[mt * 4 + j] = sacc[j] * 0.125f;
            }
            float cm = vals[0];
#pragma unroll
            for (int i = 1; i < 16; ++i) cm = fmaxf(cm, vals[i]);
            cm = fmaxf(cm, __shfl_xor(cm, 16));
            cm = fmaxf(cm, __shfl_xor(cm, 32));
            float newm = fmaxf(m_run[ntl], cm);
            l_run[ntl] *= __expf(m_run[ntl] - newm);
            m_run[ntl] = newm;
            float ps = 0.f;
#pragma unroll
            for (int i = 0; i < 16; ++i) ps += __expf(vals[i] - newm);
            ps += __shfl_xor(ps, 16);
            ps += __shfl_xor(ps, 32);
            l_run[ntl] += ps;
        }
    }
    if (lg == 0) {
#pragma unroll
        for (int ntl = 0; ntl < 2; ++ntl) {
            int sg = s0 + 16 * (2 * w + ntl) + lr;
            m_ws[head * SEQ + sg]  = m_run[ntl];
            rl_ws[head * SEQ + sg] = 1.0f / l_run[ntl];
        }
    }
}

__global__ __launch_bounds__(256) void qkv_attn_kernel(
    const float* __restrict__ qkv, const float* __restrict__ m_ws,
    const float* __restrict__ rl_ws, float* __restrict__ out)
{
    __shared__ __attribute__((aligned(16))) unsigned short Ql[128 * 64];
    __shared__ __attribute__((aligned(16))) unsigned short Kl[64 * 64];
    __shared__ __attribute__((aligned(16))) unsigned short Vl[64 * 64];
    __shared__ __attribute__((aligned(16))) unsigned short Pl[128 * 64];
    const int head = blockIdx.x >> 4, ttile = blockIdx.x & 15, t0 = ttile * 128;
    const int b = head >> 3, h = head & 7;
    const float* qp  = qkv + (size_t)(b * 1536 + h * 192) * SEQ;
    const float* kp  = qp + (size_t)CHD * SEQ;
    const float* vp  = qp + (size_t)(2 * CHD) * SEQ;
    const float* mh  = m_ws  + head * SEQ;
    const float* rlh = rl_ws + head * SEQ;
    const int tid = threadIdx.x, w = tid >> 6, l = tid & 63, lg = l >> 4, lr = l & 15;
    for (int idx = tid; idx < 128 * 64; idx += 256) {
        int t = idx & 127, c = idx >> 7;
        Ql[t * 64 + (c ^ ((t & 7) << 3))] = f2bf(qp[(size_t)c * SEQ + t0 + t]);
    }
    f32x4 acc[4][2];
#pragma unroll
    for (int i = 0; i < 4; ++i)
#pragma unroll
        for (int j = 0; j < 2; ++j) acc[i][j] = (f32x4){0.f, 0.f, 0.f, 0.f};
    for (int sc = 0; sc < 32; ++sc) {
        const int s0 = sc * 64;
        __syncthreads();
        for (int idx = tid; idx < 64 * 64; idx += 256) {
            int s = idx & 63, c = idx >> 6;
            Kl[s * 64 + (c ^ ((s & 7) << 3))] = f2bf(kp[(size_t)c * SEQ + s0 + s]);
            Vl[c * 64 + (s ^ ((c & 7) << 3))] = f2bf(vp[(size_t)c * SEQ + s0 + s] * rlh[s0 + s]);
        }
        __syncthreads();
        float msv[4];
#pragma unroll
        for (int nts = 0; nts < 4; ++nts) msv[nts] = mh[s0 + 16 * nts + lr];
#pragma unroll
        for (int mts = 0; mts < 2; ++mts) {
            const int trowbase = 16 * (2 * w + mts);
#pragma unroll
            for (int nts = 0; nts < 4; ++nts) {
                f32x4 sa = {0.f, 0.f, 0.f, 0.f};
#pragma unroll
                for (int kk = 0; kk < 2; ++kk) {
                    bf16x8 a  = lds_frag(Ql, trowbase + lr, 32 * kk + 8 * lg);
                    bf16x8 bk = lds_frag(Kl, 16 * nts + lr, 32 * kk + 8 * lg);
                    sa = __builtin_amdgcn_mfma_f32_16x16x32_bf16(a, bk, sa, 0, 0, 0);
                }
                const int scol = 16 * nts + lr;
#pragma unroll
                for (int j = 0; j < 4; ++j) {
                    int trow = trowbase + 4 * lg + j;
                    float p = __expf(sa[j] * 0.125f - msv[nts]);
                    Pl[trow * 64 + (scol ^ ((trow & 7) << 3))] = f2bf(p);
                }
            }
        }
#pragma unroll
        for (int mt = 0; mt < 4; ++mt) {
#pragma unroll
            for (int ntl = 0; ntl < 2; ++ntl) {
                const int trow = 16 * (2 * w + ntl);
#pragma unroll
                for (int kk = 0; kk < 2; ++kk) {
                    bf16x8 a  = lds_frag(Vl, 16 * mt + lr, 32 * kk + 8 * lg);
                    bf16x8 bp = lds_frag(Pl, trow + lr,    32 * kk + 8 * lg);
                    acc[mt][ntl] = __builtin_amdgcn_mfma_f32_16x16x32_bf16(a, bp, acc[mt][ntl], 0, 0, 0);
                }
            }
        }
    }
    float* op = out + (size_t)(b * 512 + h * 64) * SEQ;
#pragma unroll
    for (int mt = 0; mt < 4; ++mt) {
#pragma unroll
        for (int ntl = 0; ntl < 2; ++ntl) {
            int tcol = t0 + 16 * (2 * w + ntl) + lr;
#pragma unroll
            for (int j = 0; j < 4; ++j) {
                int c = 16 * mt + 4 * lg + j;
                op[(size_t)c * SEQ + tcol] = acc[mt][ntl][j];
            }
        }
    }
}

// ================================================================ launch
extern "C" void kernel_launch(void* const* d_in, const int* in_sizes, int n_in,
                              void* d_out, int out_size, void* d_ws, size_t ws_size,
                              hipStream_t stream) {
    const float* qkv = (const float*)d_in[0];
    float* out = (float*)d_out;
    (void)in_sizes; (void)n_in; (void)out_size;

    const size_t need = (size_t)3 * NHB * SEQ * CHD * 2;   // 24 MB bf16 buffers
    if (ws_size >= need) {
        unsigned short* Qt = (unsigned short*)d_ws;
        unsigned short* Kt = Qt + (size_t)NHB * SEQ * CHD;
        unsigned short* Vb = Kt + (size_t)NHB * SEQ * CHD;
        convert_qk    <<<dim3(NHB * 16), dim3(256), 0, stream>>>(qkv, Qt, Kt);
        stats10_kernel<<<dim3(256),      dim3(512), 0, stream>>>(qkv, Qt, Kt, Vb);
        attn13_kernel <<<dim3(256),      dim3(512), 0, stream>>>(Qt, Kt, Vb, out);
    } else {
        float* m_ws  = (float*)d_ws;
        float* rl_ws = m_ws + (size_t)NHB * SEQ;
        qkv_stats_kernel<<<dim3(NHB * 16), dim3(256), 0, stream>>>(qkv, m_ws, rl_ws);
        qkv_attn_kernel <<<dim3(NHB * 16), dim3(256), 0, stream>>>(qkv, m_ws, rl_ws, out);
    }
}